// Round 1
// 323.912 us; speedup vs baseline: 1.0455x; 1.0455x over previous
//
#include <hip/hip_runtime.h>
#include <hip/hip_fp16.h>
#include <math.h>

// GAT 2-layer. R14: agg kernels rewritten with shuffle-free lane mapping
// (e=lane>>3, hh=lane&7: weight lane == channel-chunk lane, one dwordx4
// gather per 8 edges, zero ds_bpermute in loop). Fused layer-1 matvec
// moved out of agg8 into MFMA kernel kTF1 (K=64, gemm_body pattern).

#define CAPS 48
#define STRIDE 49
#define NBMAX 128

typedef _Float16 h2_t  __attribute__((ext_vector_type(2)));
typedef _Float16 h8_t  __attribute__((ext_vector_type(8)));
typedef float    f4_t  __attribute__((ext_vector_type(4)));

__device__ __forceinline__ float lrelu(float v) { return v >= 0.f ? v : 0.2f * v; }
__device__ __forceinline__ float eluf(float v)  { return v > 0.f ? v : expm1f(v); }

// ---------------- prep: swizzled fp16 B-images ----------------
// W0 image: [ct 0..4][ks 0..3][quad][col][j]  (1280 x 8 half)
// W1 image: [ct 0..3][ks 0..1][quad][col][j]  (512 x 8 half)
__global__ void kPrep(const float* __restrict__ W0,
                      const float* __restrict__ aS0, const float* __restrict__ aD0,
                      const float* __restrict__ W1,
                      __half* __restrict__ W0swz, __half* __restrict__ W1swz)
{
    for (int g = threadIdx.x; g < 1280; g += 256) {
        int col  = g & 15;
        int quad = (g >> 4) & 3;
        int ks   = (g >> 6) & 3;
        int ct   = g >> 8;
        #pragma unroll
        for (int j = 0; j < 8; j++) {
            int k = ks * 32 + quad * 8 + j;
            float v;
            if (ct < 4) {
                v = W0[k * 64 + ct * 16 + col];
            } else {
                int h = col & 7;
                const float* att = (col < 8) ? aS0 : aD0;
                v = 0.f;
                #pragma unroll
                for (int cc = 0; cc < 8; cc++)
                    v += W0[k * 64 + h * 8 + cc] * att[h * 8 + cc];
            }
            W0swz[g * 8 + j] = __float2half(v);
        }
    }
    for (int g = threadIdx.x; g < 512; g += 256) {
        int col  = g & 15;
        int quad = (g >> 4) & 3;
        int ks   = (g >> 6) & 1;
        int ct   = g >> 7;
        #pragma unroll
        for (int j = 0; j < 8; j++) {
            int k = ks * 32 + quad * 8 + j;
            W1swz[g * 8 + j] = __float2half(W1[k * 64 + ct * 16 + col]);
        }
    }
}

// ---------------- tf0 MFMA body: 8 waves/block(512), 16 rows/wave -------------
__device__ __forceinline__ void gemm_body(
    int gb, const float* __restrict__ x, int N,
    __half* __restrict__ xw, float* __restrict__ as, float* __restrict__ ad,
    h8_t* Bl)
{
    int wave = threadIdx.x >> 6, lane = threadIdx.x & 63;
    int row0 = gb * 128 + wave * 16;
    if (row0 >= N) return;
    int quad = lane >> 4, c16 = lane & 15;
    int myrow = min(row0 + c16, N - 1);
    const float* xr = x + (size_t)myrow * 128;
    h8_t a[4];
    #pragma unroll
    for (int ks = 0; ks < 4; ks++) {
        int kb = ks * 32 + quad * 8;
        float4 v0 = *(const float4*)(xr + kb);
        float4 v1 = *(const float4*)(xr + kb + 4);
        h8_t av;
        av[0] = (_Float16)v0.x; av[1] = (_Float16)v0.y;
        av[2] = (_Float16)v0.z; av[3] = (_Float16)v0.w;
        av[4] = (_Float16)v1.x; av[5] = (_Float16)v1.y;
        av[6] = (_Float16)v1.z; av[7] = (_Float16)v1.w;
        a[ks] = av;
    }
    int rbase = row0 + quad * 4;
    #pragma unroll
    for (int ct = 0; ct < 5; ct++) {
        f4_t acc = {0.f, 0.f, 0.f, 0.f};
        #pragma unroll
        for (int ks = 0; ks < 4; ks++) {
            h8_t b = Bl[(ct * 4 + ks) * 64 + lane];
            acc = __builtin_amdgcn_mfma_f32_16x16x32_f16(a[ks], b, acc, 0, 0, 0);
        }
        if (ct < 4) {
            int col = ct * 16 + c16;
            #pragma unroll
            for (int r = 0; r < 4; r++) {
                int row = rbase + r;
                if (row < N) xw[(size_t)row * 64 + col] = __float2half(acc[r]);
            }
        } else {
            #pragma unroll
            for (int r = 0; r < 4; r++) {
                int row = rbase + r;
                if (row < N) {
                    if (c16 < 8) as[(size_t)row * 8 + c16] = acc[r];
                    else         ad[(size_t)row * 8 + (c16 - 8)] = acc[r];
                }
            }
        }
    }
}

// ---------------- fused: gemm0 || single-pass binning ----------------
__global__ __launch_bounds__(512, 4) void kGB(
    const float* __restrict__ x, const __half* __restrict__ W0swz, int N,
    __half* __restrict__ xw, float* __restrict__ as, float* __restrict__ ad,
    int gemmBlocks,
    const int* __restrict__ src, const int* __restrict__ dst, int E, int perBlock,
    unsigned* __restrict__ bucketBuf, int* __restrict__ gcur, int NB, int cap,
    int binBlocks)
{
    __shared__ __align__(16) char smem[NBMAX * STRIDE * 4 + NBMAX * 4]; // 25.6 KB union
    int b = blockIdx.x;
    int T = gemmBlocks + binBlocks;
    int lo = (int)((long long)b * gemmBlocks / T);
    int hi = (int)((long long)(b + 1) * gemmBlocks / T);
    if (hi > lo) {
        h8_t* Bl = (h8_t*)smem;
        const float4* s = (const float4*)W0swz;
        float4* d = (float4*)smem;
        for (int i = threadIdx.x; i < 1280; i += 512) d[i] = s[i];
        __syncthreads();
        gemm_body(lo, x, N, xw, as, ad, Bl);
    } else {
        int pb = b - hi;
        unsigned* stage = (unsigned*)smem;
        int* scnt = (int*)(smem + NBMAX * STRIDE * 4);
        int tid = threadIdx.x;
        for (int i = tid; i < NB; i += 512) scnt[i] = 0;
        __syncthreads();
        int e0 = pb * perBlock, e1 = min(E, e0 + perBlock);
        for (int i = e0 + tid; i < e1; i += 512) {
            int d2 = dst[i], s2 = src[i];
            int bk = d2 >> 10;
            unsigned rec = ((unsigned)(d2 & 1023) << 22) | (unsigned)s2;
            int pos = atomicAdd(&scnt[bk], 1);
            if (pos < CAPS) {
                stage[bk * STRIDE + pos] = rec;
            } else {
                int g = atomicAdd(&gcur[bk], 1);
                bucketBuf[(size_t)bk * cap + g] = rec;
            }
        }
        __syncthreads();
        if (tid < NB) {
            int n = min(scnt[tid], CAPS);
            if (n > 0) {
                int gb2 = atomicAdd(&gcur[tid], n);
                unsigned* gp = &bucketBuf[(size_t)tid * cap + gb2];
                for (int j = 0; j < n; j++) gp[j] = stage[tid * STRIDE + j];
            }
        }
    }
}

// ---------------- phase2: per-bucket CSR build ----------------
__global__ __launch_bounds__(256) void kP2(
    const unsigned* __restrict__ bucketBuf, const int* __restrict__ gcur,
    int NB, int cap, int N, int* __restrict__ row, int* __restrict__ adj)
{
    __shared__ int deg[1024];
    __shared__ int curl[1024];
    __shared__ int sc[256];
    int b = blockIdx.x, tid = threadIdx.x;
    int lo = b << 10;
    int hi = min(N, lo + 1024);
    int cnt = hi - lo;
    int size = min(gcur[b], cap);
    sc[tid] = (tid < b) ? gcur[tid] : 0;
    __syncthreads();
    for (int off = 128; off > 0; off >>= 1) {
        if (tid < off) sc[tid] += sc[tid + off];
        __syncthreads();
    }
    int bbase = sc[0];
    __syncthreads();
    for (int i = tid; i < 1024; i += 256) deg[i] = 0;
    __syncthreads();
    const unsigned* buf = bucketBuf + (size_t)b * cap;
    for (int e = tid; e < size; e += 256) atomicAdd(&deg[buf[e] >> 22], 1);
    __syncthreads();
    int dv[4]; int s = 0;
    #pragma unroll
    for (int j = 0; j < 4; j++) { dv[j] = deg[tid * 4 + j]; s += dv[j]; }
    sc[tid] = s; __syncthreads();
    for (int off = 1; off < 256; off <<= 1) {
        int xv = (tid >= off) ? sc[tid - off] : 0;
        __syncthreads();
        sc[tid] += xv;
        __syncthreads();
    }
    int o = (tid ? sc[tid - 1] : 0);
    #pragma unroll
    for (int j = 0; j < 4; j++) {
        int loc = tid * 4 + j;
        curl[loc] = o;
        if (loc < cnt) row[lo + loc] = bbase + o;
        o += dv[j];
    }
    if (b == NB - 1 && tid == 0) row[N] = bbase + size;
    __syncthreads();
    for (int e = tid; e < size; e += 256) {
        unsigned r = buf[e];
        int l = r >> 22;
        int p = atomicAdd(&curl[l], 1);
        adj[bbase + p] = (int)(r & 0x3FFFFF);
    }
}

// ---------------- layer0 aggregation (shuffle-free lane mapping) -----------
// lane = e*8 + hh ; e = edge slot (8 edges/group), hh = head == 16B chunk.
// Weight for head hh of edge e is computed on the exact lane that needs it.
__global__ __launch_bounds__(256) void k_agg8(
    const __half* __restrict__ xw, const float* __restrict__ as, const float* __restrict__ ad,
    const int* __restrict__ row, const int* __restrict__ adj,
    const float* __restrict__ bias, int N, __half* __restrict__ hbuf)
{
    int n = (blockIdx.x * 256 + threadIdx.x) >> 6;
    int lane = threadIdx.x & 63;
    if (n >= N) return;
    int e8 = lane >> 3;
    int hh = lane & 7;
    int rs = row[n], re = row[n + 1];
    float adv = ad[(size_t)n * 8 + hh];
    float shift = lrelu(as[(size_t)n * 8 + hh] + adv);
    float accv[8];
    #pragma unroll
    for (int k = 0; k < 8; k++) accv[k] = 0.f;
    float dsum = 0.f;
    int j = rs;
    bool vC = (j + e8) < re;
    int  sC = adj[vC ? j + e8 : 0];
    float eC = lrelu(as[(size_t)sC * 8 + hh] + adv);
    h8_t xvC = *(const h8_t*)(xw + (size_t)sC * 64 + hh * 8);
    while (j < re) {
        int jn = j + 8;
        bool vN = (jn + e8) < re;
        int  sN = adj[vN ? jn + e8 : 0];
        float w = vC ? __expf(eC - shift) : 0.f;
        dsum += w;
        float eN = lrelu(as[(size_t)sN * 8 + hh] + adv);
        h8_t xvN = *(const h8_t*)(xw + (size_t)sN * 64 + hh * 8);
        #pragma unroll
        for (int k = 0; k < 8; k++) accv[k] = fmaf(w, (float)xvC[k], accv[k]);
        sC = sN; eC = eN; vC = vN; xvC = xvN; j = jn;
    }
    #pragma unroll
    for (int k = 0; k < 8; k++) {
        accv[k] += __shfl_xor(accv[k], 8, 64);
        accv[k] += __shfl_xor(accv[k], 16, 64);
        accv[k] += __shfl_xor(accv[k], 32, 64);
    }
    dsum += __shfl_xor(dsum, 8, 64);
    dsum += __shfl_xor(dsum, 16, 64);
    dsum += __shfl_xor(dsum, 32, 64);
    if (e8 == 0) {
        float inv = 1.f / (1.f + dsum);
        h8_t sv = *(const h8_t*)(xw + (size_t)n * 64 + hh * 8);
        float4 b0 = *(const float4*)(bias + hh * 8);
        float4 b1 = *(const float4*)(bias + hh * 8 + 4);
        float bb[8] = {b0.x, b0.y, b0.z, b0.w, b1.x, b1.y, b1.z, b1.w};
        h8_t o;
        #pragma unroll
        for (int k = 0; k < 8; k++) {
            float v = (accv[k] + (float)sv[k]) * inv + bb[k];
            o[k] = (_Float16)eluf(v);
        }
        *(h8_t*)(hbuf + (size_t)n * 64 + hh * 8) = o;
    }
}

// ---------------- layer1 transform: h @ W1 via MFMA (K=64) + as1/ad1 --------
__global__ __launch_bounds__(512, 4) void kTF1(
    const __half* __restrict__ h, const __half* __restrict__ W1swz,
    const float* __restrict__ aS1, const float* __restrict__ aD1, int N,
    __half* __restrict__ hw, float* __restrict__ as1, float* __restrict__ ad1)
{
    __shared__ __align__(16) h8_t Bl[512];
    {
        const float4* s = (const float4*)W1swz;
        float4* d = (float4*)Bl;
        for (int i = threadIdx.x; i < 512; i += 512) d[i] = s[i];
    }
    __syncthreads();
    int wave = threadIdx.x >> 6, lane = threadIdx.x & 63;
    int row0 = blockIdx.x * 128 + wave * 16;
    if (row0 >= N) return;
    int quad = lane >> 4, c16 = lane & 15;
    int myrow = min(row0 + c16, N - 1);
    const __half* hr = h + (size_t)myrow * 64;
    h8_t a0 = *(const h8_t*)(hr + quad * 8);
    h8_t a1 = *(const h8_t*)(hr + 32 + quad * 8);
    int rbase = row0 + quad * 4;
    float ps[4] = {0.f, 0.f, 0.f, 0.f};
    float pd[4] = {0.f, 0.f, 0.f, 0.f};
    #pragma unroll
    for (int ct = 0; ct < 4; ct++) {
        f4_t acc = {0.f, 0.f, 0.f, 0.f};
        acc = __builtin_amdgcn_mfma_f32_16x16x32_f16(a0, Bl[(ct * 2 + 0) * 64 + lane], acc, 0, 0, 0);
        acc = __builtin_amdgcn_mfma_f32_16x16x32_f16(a1, Bl[(ct * 2 + 1) * 64 + lane], acc, 0, 0, 0);
        float s1c = aS1[ct * 16 + c16];
        float d1c = aD1[ct * 16 + c16];
        int col = ct * 16 + c16;
        #pragma unroll
        for (int r = 0; r < 4; r++) {
            int rr = rbase + r;
            if (rr < N) hw[(size_t)rr * 64 + col] = __float2half(acc[r]);
            ps[r] = fmaf(acc[r], s1c, ps[r]);
            pd[r] = fmaf(acc[r], d1c, pd[r]);
        }
    }
    #pragma unroll
    for (int r = 0; r < 4; r++) {
        #pragma unroll
        for (int off = 1; off < 16; off <<= 1) {
            ps[r] += __shfl_xor(ps[r], off, 64);
            pd[r] += __shfl_xor(pd[r], off, 64);
        }
    }
    if (c16 == 0) {
        #pragma unroll
        for (int r = 0; r < 4; r++) {
            int rr = rbase + r;
            if (rr < N) { as1[rr] = ps[r]; ad1[rr] = pd[r]; }
        }
    }
}

// ---------------- layer1 aggregation (shuffle-free, single head) ------------
__global__ __launch_bounds__(256) void k_agg1(
    const __half* __restrict__ hw, const float* __restrict__ as, const float* __restrict__ ad,
    const int* __restrict__ row, const int* __restrict__ adj,
    const float* __restrict__ bias, int N, float* __restrict__ outp)
{
    int n = (blockIdx.x * 256 + threadIdx.x) >> 6;
    int lane = threadIdx.x & 63;
    if (n >= N) return;
    int e8 = lane >> 3;
    int hh = lane & 7;
    int rs = row[n], re = row[n + 1];
    float adv = ad[n];
    float shift = lrelu(as[n] + adv);
    float accv[8];
    #pragma unroll
    for (int k = 0; k < 8; k++) accv[k] = 0.f;
    float dsum = 0.f;
    int j = rs;
    bool vC = (j + e8) < re;
    int  sC = adj[vC ? j + e8 : 0];
    float eC = lrelu(as[sC] + adv);
    h8_t xvC = *(const h8_t*)(hw + (size_t)sC * 64 + hh * 8);
    while (j < re) {
        int jn = j + 8;
        bool vN = (jn + e8) < re;
        int  sN = adj[vN ? jn + e8 : 0];
        float w = vC ? __expf(eC - shift) : 0.f;
        dsum += w;
        float eN = lrelu(as[sN] + adv);
        h8_t xvN = *(const h8_t*)(hw + (size_t)sN * 64 + hh * 8);
        #pragma unroll
        for (int k = 0; k < 8; k++) accv[k] = fmaf(w, (float)xvC[k], accv[k]);
        sC = sN; eC = eN; vC = vN; xvC = xvN; j = jn;
    }
    #pragma unroll
    for (int k = 0; k < 8; k++) {
        accv[k] += __shfl_xor(accv[k], 8, 64);
        accv[k] += __shfl_xor(accv[k], 16, 64);
        accv[k] += __shfl_xor(accv[k], 32, 64);
    }
    dsum += __shfl_xor(dsum, 8, 64);
    dsum += __shfl_xor(dsum, 16, 64);
    dsum += __shfl_xor(dsum, 32, 64);
    if (e8 == 0) {
        float inv = 1.f / (1.f + dsum);
        h8_t sv = *(const h8_t*)(hw + (size_t)n * 64 + hh * 8);
        float4 b0 = *(const float4*)(bias + hh * 8);
        float4 b1 = *(const float4*)(bias + hh * 8 + 4);
        float bb[8] = {b0.x, b0.y, b0.z, b0.w, b1.x, b1.y, b1.z, b1.w};
        float ov[8];
        #pragma unroll
        for (int k = 0; k < 8; k++)
            ov[k] = eluf((accv[k] + (float)sv[k]) * inv + bb[k]);
        float4 o0 = {ov[0], ov[1], ov[2], ov[3]};
        float4 o1 = {ov[4], ov[5], ov[6], ov[7]};
        float4* op = (float4*)(outp + (size_t)n * 64 + hh * 8);
        op[0] = o0;
        op[1] = o1;
    }
}

extern "C" void kernel_launch(void* const* d_in, const int* in_sizes, int n_in,
                              void* d_out, int out_size, void* d_ws, size_t ws_size,
                              hipStream_t stream)
{
    const float* x   = (const float*)d_in[0];
    const int*   ei  = (const int*)d_in[1];
    const float* W0  = (const float*)d_in[2];
    const float* aS0 = (const float*)d_in[3];
    const float* aD0 = (const float*)d_in[4];
    const float* b0  = (const float*)d_in[5];
    const float* W1  = (const float*)d_in[6];
    const float* aS1 = (const float*)d_in[7];
    const float* aD1 = (const float*)d_in[8];
    const float* b1  = (const float*)d_in[9];

    const int N = in_sizes[0] / 128;
    const int E = in_sizes[1] / 2;
    const int* srcp = ei;
    const int* dstp = ei + E;

    const int NB  = (N + 1023) >> 10;
    const int cap = E / NB + 4096;

    char* ws = (char*)d_ws;
    size_t off = 0;
    auto alloc = [&](size_t bytes) -> size_t {
        size_t o = off;
        off = (o + bytes + 255) & ~(size_t)255;
        return o;
    };
    __half* B1 = (__half*)(ws + alloc((size_t)N * 64 * 2));     // xw (half); later reused as hw
    size_t b2Bytes = (size_t)N * 64 * 2;
    size_t bkBytes = (size_t)NB * cap * 4;
    char*  region  = ws + alloc(b2Bytes > bkBytes ? b2Bytes : bkBytes);
    __half*   B2        = (__half*)region;     // h overlays bucketBuf (dead after kP2)
    unsigned* bucketBuf = (unsigned*)region;
    float* as0 = (float*)(ws + alloc((size_t)N * 8 * 4));
    float* ad0 = (float*)(ws + alloc((size_t)N * 8 * 4));
    float* as1 = (float*)(ws + alloc((size_t)N * 4));
    float* ad1 = (float*)(ws + alloc((size_t)N * 4));
    int*   row = (int*)(ws + alloc((size_t)(N + 1) * 4));
    int*   adj = (int*)(ws + alloc((size_t)E * 4));
    int*  gcur = (int*)(ws + alloc((size_t)NB * 4));
    __half* W0swz = (__half*)(ws + alloc(1280 * 8 * 2));
    __half* W1swz = (__half*)(ws + alloc(512 * 8 * 2));

    const int gemmBlocks = (N + 127) / 128;
    const int binBlocks  = 1024;
    const int perBlock   = (E + binBlocks - 1) / binBlocks;

    hipMemsetAsync(gcur, 0, (size_t)NB * 4, stream);
    kPrep<<<1, 256, 0, stream>>>(W0, aS0, aD0, W1, W0swz, W1swz);
    kGB<<<gemmBlocks + binBlocks, 512, 0, stream>>>(
        x, W0swz, N, B1, as0, ad0, gemmBlocks,
        srcp, dstp, E, perBlock, bucketBuf, gcur, NB, cap, binBlocks);
    kP2<<<NB, 256, 0, stream>>>(bucketBuf, gcur, NB, cap, N, row, adj);

    const int agBlocks = (N + 3) / 4;
    // layer-0 aggregation: reads xw (B1), writes h (B2, over dead bucketBuf)
    k_agg8<<<agBlocks, 256, 0, stream>>>(B1, as0, ad0, row, adj, b0, N, B2);
    // layer-1 transform: reads h (B2), writes hw into B1 (xw dead) + as1/ad1
    kTF1<<<(N + 127) / 128, 512, 0, stream>>>(B2, W1swz, aS1, aD1, N, B1, as1, ad1);
    // layer-1 aggregation
    k_agg1<<<agBlocks, 256, 0, stream>>>(B1, as1, ad1, row, adj, b1, N, (float*)d_out);
}

// Round 2
// 296.786 us; speedup vs baseline: 1.1411x; 1.0914x over previous
//
#include <hip/hip_runtime.h>
#include <hip/hip_fp16.h>
#include <math.h>

// GAT 2-layer. R15: agg kernels — 2 nodes per wave (32 lanes/node: 4 edge
// slots x 8 head-chunks) to halve per-node fixed cost, and all gather
// indices switched to unsigned 32-bit so the compiler emits saddr-form
// global loads (1 VALU per address instead of ~5 of 64-bit math).

#define CAPS 48
#define STRIDE 49
#define NBMAX 128

typedef _Float16 h2_t  __attribute__((ext_vector_type(2)));
typedef _Float16 h8_t  __attribute__((ext_vector_type(8)));
typedef float    f4_t  __attribute__((ext_vector_type(4)));

__device__ __forceinline__ float lrelu(float v) { return v >= 0.f ? v : 0.2f * v; }
__device__ __forceinline__ float eluf(float v)  { return v > 0.f ? v : expm1f(v); }

// ---------------- prep: swizzled fp16 B-images ----------------
// W0 image: [ct 0..4][ks 0..3][quad][col][j]  (1280 x 8 half)
// W1 image: [ct 0..3][ks 0..1][quad][col][j]  (512 x 8 half)
__global__ void kPrep(const float* __restrict__ W0,
                      const float* __restrict__ aS0, const float* __restrict__ aD0,
                      const float* __restrict__ W1,
                      __half* __restrict__ W0swz, __half* __restrict__ W1swz)
{
    for (int g = threadIdx.x; g < 1280; g += 256) {
        int col  = g & 15;
        int quad = (g >> 4) & 3;
        int ks   = (g >> 6) & 3;
        int ct   = g >> 8;
        #pragma unroll
        for (int j = 0; j < 8; j++) {
            int k = ks * 32 + quad * 8 + j;
            float v;
            if (ct < 4) {
                v = W0[k * 64 + ct * 16 + col];
            } else {
                int h = col & 7;
                const float* att = (col < 8) ? aS0 : aD0;
                v = 0.f;
                #pragma unroll
                for (int cc = 0; cc < 8; cc++)
                    v += W0[k * 64 + h * 8 + cc] * att[h * 8 + cc];
            }
            W0swz[g * 8 + j] = __float2half(v);
        }
    }
    for (int g = threadIdx.x; g < 512; g += 256) {
        int col  = g & 15;
        int quad = (g >> 4) & 3;
        int ks   = (g >> 6) & 1;
        int ct   = g >> 7;
        #pragma unroll
        for (int j = 0; j < 8; j++) {
            int k = ks * 32 + quad * 8 + j;
            W1swz[g * 8 + j] = __float2half(W1[k * 64 + ct * 16 + col]);
        }
    }
}

// ---------------- tf0 MFMA body: 8 waves/block(512), 16 rows/wave -------------
__device__ __forceinline__ void gemm_body(
    int gb, const float* __restrict__ x, int N,
    __half* __restrict__ xw, float* __restrict__ as, float* __restrict__ ad,
    h8_t* Bl)
{
    int wave = threadIdx.x >> 6, lane = threadIdx.x & 63;
    int row0 = gb * 128 + wave * 16;
    if (row0 >= N) return;
    int quad = lane >> 4, c16 = lane & 15;
    int myrow = min(row0 + c16, N - 1);
    const float* xr = x + (size_t)myrow * 128;
    h8_t a[4];
    #pragma unroll
    for (int ks = 0; ks < 4; ks++) {
        int kb = ks * 32 + quad * 8;
        float4 v0 = *(const float4*)(xr + kb);
        float4 v1 = *(const float4*)(xr + kb + 4);
        h8_t av;
        av[0] = (_Float16)v0.x; av[1] = (_Float16)v0.y;
        av[2] = (_Float16)v0.z; av[3] = (_Float16)v0.w;
        av[4] = (_Float16)v1.x; av[5] = (_Float16)v1.y;
        av[6] = (_Float16)v1.z; av[7] = (_Float16)v1.w;
        a[ks] = av;
    }
    int rbase = row0 + quad * 4;
    #pragma unroll
    for (int ct = 0; ct < 5; ct++) {
        f4_t acc = {0.f, 0.f, 0.f, 0.f};
        #pragma unroll
        for (int ks = 0; ks < 4; ks++) {
            h8_t b = Bl[(ct * 4 + ks) * 64 + lane];
            acc = __builtin_amdgcn_mfma_f32_16x16x32_f16(a[ks], b, acc, 0, 0, 0);
        }
        if (ct < 4) {
            int col = ct * 16 + c16;
            #pragma unroll
            for (int r = 0; r < 4; r++) {
                int row = rbase + r;
                if (row < N) xw[(size_t)row * 64 + col] = __float2half(acc[r]);
            }
        } else {
            #pragma unroll
            for (int r = 0; r < 4; r++) {
                int row = rbase + r;
                if (row < N) {
                    if (c16 < 8) as[(size_t)row * 8 + c16] = acc[r];
                    else         ad[(size_t)row * 8 + (c16 - 8)] = acc[r];
                }
            }
        }
    }
}

// ---------------- fused: gemm0 || single-pass binning ----------------
__global__ __launch_bounds__(512, 4) void kGB(
    const float* __restrict__ x, const __half* __restrict__ W0swz, int N,
    __half* __restrict__ xw, float* __restrict__ as, float* __restrict__ ad,
    int gemmBlocks,
    const int* __restrict__ src, const int* __restrict__ dst, int E, int perBlock,
    unsigned* __restrict__ bucketBuf, int* __restrict__ gcur, int NB, int cap,
    int binBlocks)
{
    __shared__ __align__(16) char smem[NBMAX * STRIDE * 4 + NBMAX * 4]; // 25.6 KB union
    int b = blockIdx.x;
    int T = gemmBlocks + binBlocks;
    int lo = (int)((long long)b * gemmBlocks / T);
    int hi = (int)((long long)(b + 1) * gemmBlocks / T);
    if (hi > lo) {
        h8_t* Bl = (h8_t*)smem;
        const float4* s = (const float4*)W0swz;
        float4* d = (float4*)smem;
        for (int i = threadIdx.x; i < 1280; i += 512) d[i] = s[i];
        __syncthreads();
        gemm_body(lo, x, N, xw, as, ad, Bl);
    } else {
        int pb = b - hi;
        unsigned* stage = (unsigned*)smem;
        int* scnt = (int*)(smem + NBMAX * STRIDE * 4);
        int tid = threadIdx.x;
        for (int i = tid; i < NB; i += 512) scnt[i] = 0;
        __syncthreads();
        int e0 = pb * perBlock, e1 = min(E, e0 + perBlock);
        for (int i = e0 + tid; i < e1; i += 512) {
            int d2 = dst[i], s2 = src[i];
            int bk = d2 >> 10;
            unsigned rec = ((unsigned)(d2 & 1023) << 22) | (unsigned)s2;
            int pos = atomicAdd(&scnt[bk], 1);
            if (pos < CAPS) {
                stage[bk * STRIDE + pos] = rec;
            } else {
                int g = atomicAdd(&gcur[bk], 1);
                bucketBuf[(size_t)bk * cap + g] = rec;
            }
        }
        __syncthreads();
        if (tid < NB) {
            int n = min(scnt[tid], CAPS);
            if (n > 0) {
                int gb2 = atomicAdd(&gcur[tid], n);
                unsigned* gp = &bucketBuf[(size_t)tid * cap + gb2];
                for (int j = 0; j < n; j++) gp[j] = stage[tid * STRIDE + j];
            }
        }
    }
}

// ---------------- phase2: per-bucket CSR build ----------------
__global__ __launch_bounds__(256) void kP2(
    const unsigned* __restrict__ bucketBuf, const int* __restrict__ gcur,
    int NB, int cap, int N, int* __restrict__ row, int* __restrict__ adj)
{
    __shared__ int deg[1024];
    __shared__ int curl[1024];
    __shared__ int sc[256];
    int b = blockIdx.x, tid = threadIdx.x;
    int lo = b << 10;
    int hi = min(N, lo + 1024);
    int cnt = hi - lo;
    int size = min(gcur[b], cap);
    sc[tid] = (tid < b) ? gcur[tid] : 0;
    __syncthreads();
    for (int off = 128; off > 0; off >>= 1) {
        if (tid < off) sc[tid] += sc[tid + off];
        __syncthreads();
    }
    int bbase = sc[0];
    __syncthreads();
    for (int i = tid; i < 1024; i += 256) deg[i] = 0;
    __syncthreads();
    const unsigned* buf = bucketBuf + (size_t)b * cap;
    for (int e = tid; e < size; e += 256) atomicAdd(&deg[buf[e] >> 22], 1);
    __syncthreads();
    int dv[4]; int s = 0;
    #pragma unroll
    for (int j = 0; j < 4; j++) { dv[j] = deg[tid * 4 + j]; s += dv[j]; }
    sc[tid] = s; __syncthreads();
    for (int off = 1; off < 256; off <<= 1) {
        int xv = (tid >= off) ? sc[tid - off] : 0;
        __syncthreads();
        sc[tid] += xv;
        __syncthreads();
    }
    int o = (tid ? sc[tid - 1] : 0);
    #pragma unroll
    for (int j = 0; j < 4; j++) {
        int loc = tid * 4 + j;
        curl[loc] = o;
        if (loc < cnt) row[lo + loc] = bbase + o;
        o += dv[j];
    }
    if (b == NB - 1 && tid == 0) row[N] = bbase + size;
    __syncthreads();
    for (int e = tid; e < size; e += 256) {
        unsigned r = buf[e];
        int l = r >> 22;
        int p = atomicAdd(&curl[l], 1);
        adj[bbase + p] = (int)(r & 0x3FFFFF);
    }
}

// ---------------- layer0 aggregation: 2 nodes/wave, 32-bit saddr gathers ----
// wave = 2 halves of 32 lanes; each half owns one node. Within a half:
// e4 = sub>>3 (4 edge slots), hh = sub&7 (head == 16B chunk). The softmax
// weight for (edge, head) is computed on the exact lane that accumulates it.
__global__ __launch_bounds__(256) void k_agg8(
    const __half* __restrict__ xw, const float* __restrict__ as, const float* __restrict__ ad,
    const int* __restrict__ row, const int* __restrict__ adj,
    const float* __restrict__ bias, int N, __half* __restrict__ hbuf)
{
    int n = (blockIdx.x * 256 + threadIdx.x) >> 5;   // 8 nodes per block
    int lane = threadIdx.x & 63;
    int sub  = lane & 31;
    if (n >= N) return;
    int e4 = sub >> 3;
    int hh = sub & 7;
    int rs = row[n], re = row[n + 1];
    const h8_t* xwv = (const h8_t*)xw;               // row stride = 8 h8-chunks
    float adv = ad[(unsigned)n * 8u + hh];
    float shift = lrelu(as[(unsigned)n * 8u + hh] + adv);
    float accv[8];
    #pragma unroll
    for (int k = 0; k < 8; k++) accv[k] = 0.f;
    float dsum = 0.f;

    int j = rs + e4;
    bool vC = j < re;
    int  sC = adj[(unsigned)(vC ? j : rs)];
    float eC = lrelu(as[(unsigned)sC * 8u + hh] + adv);
    h8_t xvC = xwv[(unsigned)sC * 8u + hh];
    for (;;) {
        int jn = j + 4;
        bool vN = jn < re;
        int  sN = adj[(unsigned)(vN ? jn : rs)];
        float w = vC ? __expf(eC - shift) : 0.f;
        dsum += w;
        float eN = lrelu(as[(unsigned)sN * 8u + hh] + adv);
        h8_t xvN = xwv[(unsigned)sN * 8u + hh];
        #pragma unroll
        for (int k = 0; k < 8; k++) accv[k] = fmaf(w, (float)xvC[k], accv[k]);
        j = jn; vC = vN; sC = sN; eC = eN; xvC = xvN;
        if (!__any(vC)) break;
    }
    #pragma unroll
    for (int k = 0; k < 8; k++) {
        accv[k] += __shfl_xor(accv[k], 8, 64);
        accv[k] += __shfl_xor(accv[k], 16, 64);
    }
    dsum += __shfl_xor(dsum, 8, 64);
    dsum += __shfl_xor(dsum, 16, 64);
    if (e4 == 0) {
        float inv = 1.f / (1.f + dsum);              // self-loop weight = 1
        h8_t sv = xwv[(unsigned)n * 8u + hh];        // self-loop contribution
        float4 b0 = *(const float4*)(bias + hh * 8);
        float4 b1 = *(const float4*)(bias + hh * 8 + 4);
        float bb[8] = {b0.x, b0.y, b0.z, b0.w, b1.x, b1.y, b1.z, b1.w};
        h8_t o;
        #pragma unroll
        for (int k = 0; k < 8; k++) {
            float v = (accv[k] + (float)sv[k]) * inv + bb[k];
            o[k] = (_Float16)eluf(v);
        }
        *(h8_t*)(hbuf + (size_t)n * 64 + hh * 8) = o;
    }
}

// ---------------- layer1 transform: h @ W1 via MFMA (K=64) + as1/ad1 --------
__global__ __launch_bounds__(512, 4) void kTF1(
    const __half* __restrict__ h, const __half* __restrict__ W1swz,
    const float* __restrict__ aS1, const float* __restrict__ aD1, int N,
    __half* __restrict__ hw, float* __restrict__ as1, float* __restrict__ ad1)
{
    __shared__ __align__(16) h8_t Bl[512];
    {
        const float4* s = (const float4*)W1swz;
        float4* d = (float4*)Bl;
        for (int i = threadIdx.x; i < 512; i += 512) d[i] = s[i];
    }
    __syncthreads();
    int wave = threadIdx.x >> 6, lane = threadIdx.x & 63;
    int row0 = blockIdx.x * 128 + wave * 16;
    if (row0 >= N) return;
    int quad = lane >> 4, c16 = lane & 15;
    int myrow = min(row0 + c16, N - 1);
    const __half* hr = h + (size_t)myrow * 64;
    h8_t a0 = *(const h8_t*)(hr + quad * 8);
    h8_t a1 = *(const h8_t*)(hr + 32 + quad * 8);
    int rbase = row0 + quad * 4;
    float ps[4] = {0.f, 0.f, 0.f, 0.f};
    float pd[4] = {0.f, 0.f, 0.f, 0.f};
    #pragma unroll
    for (int ct = 0; ct < 4; ct++) {
        f4_t acc = {0.f, 0.f, 0.f, 0.f};
        acc = __builtin_amdgcn_mfma_f32_16x16x32_f16(a0, Bl[(ct * 2 + 0) * 64 + lane], acc, 0, 0, 0);
        acc = __builtin_amdgcn_mfma_f32_16x16x32_f16(a1, Bl[(ct * 2 + 1) * 64 + lane], acc, 0, 0, 0);
        float s1c = aS1[ct * 16 + c16];
        float d1c = aD1[ct * 16 + c16];
        int col = ct * 16 + c16;
        #pragma unroll
        for (int r = 0; r < 4; r++) {
            int rr = rbase + r;
            if (rr < N) hw[(size_t)rr * 64 + col] = __float2half(acc[r]);
            ps[r] = fmaf(acc[r], s1c, ps[r]);
            pd[r] = fmaf(acc[r], d1c, pd[r]);
        }
    }
    #pragma unroll
    for (int r = 0; r < 4; r++) {
        #pragma unroll
        for (int off = 1; off < 16; off <<= 1) {
            ps[r] += __shfl_xor(ps[r], off, 64);
            pd[r] += __shfl_xor(pd[r], off, 64);
        }
    }
    if (c16 == 0) {
        #pragma unroll
        for (int r = 0; r < 4; r++) {
            int rr = rbase + r;
            if (rr < N) { as1[rr] = ps[r]; ad1[rr] = pd[r]; }
        }
    }
}

// ---------------- layer1 aggregation: 2 nodes/wave, 32-bit saddr gathers ----
__global__ __launch_bounds__(256) void k_agg1(
    const __half* __restrict__ hw, const float* __restrict__ as, const float* __restrict__ ad,
    const int* __restrict__ row, const int* __restrict__ adj,
    const float* __restrict__ bias, int N, float* __restrict__ outp)
{
    int n = (blockIdx.x * 256 + threadIdx.x) >> 5;   // 8 nodes per block
    int lane = threadIdx.x & 63;
    int sub  = lane & 31;
    if (n >= N) return;
    int e4 = sub >> 3;
    int hh = sub & 7;
    int rs = row[n], re = row[n + 1];
    const h8_t* hwv = (const h8_t*)hw;
    float adv = ad[n];
    float shift = lrelu(as[n] + adv);
    float accv[8];
    #pragma unroll
    for (int k = 0; k < 8; k++) accv[k] = 0.f;
    float dsum = 0.f;

    int j = rs + e4;
    bool vC = j < re;
    int  sC = adj[(unsigned)(vC ? j : rs)];
    float eC = lrelu(as[(unsigned)sC] + adv);
    h8_t xvC = hwv[(unsigned)sC * 8u + hh];
    for (;;) {
        int jn = j + 4;
        bool vN = jn < re;
        int  sN = adj[(unsigned)(vN ? jn : rs)];
        float w = vC ? __expf(eC - shift) : 0.f;
        dsum += w;
        float eN = lrelu(as[(unsigned)sN] + adv);
        h8_t xvN = hwv[(unsigned)sN * 8u + hh];
        #pragma unroll
        for (int k = 0; k < 8; k++) accv[k] = fmaf(w, (float)xvC[k], accv[k]);
        j = jn; vC = vN; sC = sN; eC = eN; xvC = xvN;
        if (!__any(vC)) break;
    }
    #pragma unroll
    for (int k = 0; k < 8; k++) {
        accv[k] += __shfl_xor(accv[k], 8, 64);
        accv[k] += __shfl_xor(accv[k], 16, 64);
    }
    dsum += __shfl_xor(dsum, 8, 64);
    dsum += __shfl_xor(dsum, 16, 64);
    if (e4 == 0) {
        float inv = 1.f / (1.f + dsum);
        h8_t sv = hwv[(unsigned)n * 8u + hh];
        float4 b0 = *(const float4*)(bias + hh * 8);
        float4 b1 = *(const float4*)(bias + hh * 8 + 4);
        float bb[8] = {b0.x, b0.y, b0.z, b0.w, b1.x, b1.y, b1.z, b1.w};
        float ov[8];
        #pragma unroll
        for (int k = 0; k < 8; k++)
            ov[k] = eluf((accv[k] + (float)sv[k]) * inv + bb[k]);
        float4 o0 = {ov[0], ov[1], ov[2], ov[3]};
        float4 o1 = {ov[4], ov[5], ov[6], ov[7]};
        float4* op = (float4*)(outp + (size_t)n * 64 + hh * 8);
        op[0] = o0;
        op[1] = o1;
    }
}

extern "C" void kernel_launch(void* const* d_in, const int* in_sizes, int n_in,
                              void* d_out, int out_size, void* d_ws, size_t ws_size,
                              hipStream_t stream)
{
    const float* x   = (const float*)d_in[0];
    const int*   ei  = (const int*)d_in[1];
    const float* W0  = (const float*)d_in[2];
    const float* aS0 = (const float*)d_in[3];
    const float* aD0 = (const float*)d_in[4];
    const float* b0  = (const float*)d_in[5];
    const float* W1  = (const float*)d_in[6];
    const float* aS1 = (const float*)d_in[7];
    const float* aD1 = (const float*)d_in[8];
    const float* b1  = (const float*)d_in[9];

    const int N = in_sizes[0] / 128;
    const int E = in_sizes[1] / 2;
    const int* srcp = ei;
    const int* dstp = ei + E;

    const int NB  = (N + 1023) >> 10;
    const int cap = E / NB + 4096;

    char* ws = (char*)d_ws;
    size_t off = 0;
    auto alloc = [&](size_t bytes) -> size_t {
        size_t o = off;
        off = (o + bytes + 255) & ~(size_t)255;
        return o;
    };
    __half* B1 = (__half*)(ws + alloc((size_t)N * 64 * 2));     // xw (half); later reused as hw
    size_t b2Bytes = (size_t)N * 64 * 2;
    size_t bkBytes = (size_t)NB * cap * 4;
    char*  region  = ws + alloc(b2Bytes > bkBytes ? b2Bytes : bkBytes);
    __half*   B2        = (__half*)region;     // h overlays bucketBuf (dead after kP2)
    unsigned* bucketBuf = (unsigned*)region;
    float* as0 = (float*)(ws + alloc((size_t)N * 8 * 4));
    float* ad0 = (float*)(ws + alloc((size_t)N * 8 * 4));
    float* as1 = (float*)(ws + alloc((size_t)N * 4));
    float* ad1 = (float*)(ws + alloc((size_t)N * 4));
    int*   row = (int*)(ws + alloc((size_t)(N + 1) * 4));
    int*   adj = (int*)(ws + alloc((size_t)E * 4));
    int*  gcur = (int*)(ws + alloc((size_t)NB * 4));
    __half* W0swz = (__half*)(ws + alloc(1280 * 8 * 2));
    __half* W1swz = (__half*)(ws + alloc(512 * 8 * 2));

    const int gemmBlocks = (N + 127) / 128;
    const int binBlocks  = 1024;
    const int perBlock   = (E + binBlocks - 1) / binBlocks;

    hipMemsetAsync(gcur, 0, (size_t)NB * 4, stream);
    kPrep<<<1, 256, 0, stream>>>(W0, aS0, aD0, W1, W0swz, W1swz);
    kGB<<<gemmBlocks + binBlocks, 512, 0, stream>>>(
        x, W0swz, N, B1, as0, ad0, gemmBlocks,
        srcp, dstp, E, perBlock, bucketBuf, gcur, NB, cap, binBlocks);
    kP2<<<NB, 256, 0, stream>>>(bucketBuf, gcur, NB, cap, N, row, adj);

    const int agBlocks = (N + 7) / 8;   // 8 nodes per 256-thread block
    // layer-0 aggregation: reads xw (B1), writes h (B2, over dead bucketBuf)
    k_agg8<<<agBlocks, 256, 0, stream>>>(B1, as0, ad0, row, adj, b0, N, B2);
    // layer-1 transform: reads h (B2), writes hw into B1 (xw dead) + as1/ad1
    kTF1<<<(N + 127) / 128, 512, 0, stream>>>(B2, W1swz, aS1, aD1, N, B1, as1, ad1);
    // layer-1 aggregation
    k_agg1<<<agBlocks, 256, 0, stream>>>(B1, as1, ad1, row, adj, b1, N, (float*)d_out);
}

// Round 3
// 286.180 us; speedup vs baseline: 1.1834x; 1.0371x over previous
//
#include <hip/hip_runtime.h>
#include <hip/hip_fp16.h>
#include <math.h>

// GAT 2-layer. R16: agg kernels — (1) v_fma_mix_f32 inline asm (f16 operand
// consumed inline, kills 8 cvt per edge), (2) 2x edge-slot unroll (8 edges per
// node per iteration: doubles MLP + independent work between gather and use),
// (3) log2e folded into attention logits at the producers so the softmax
// weight is a bare v_exp_f32 (lrelu commutes with positive scaling).

#define CAPS 48
#define STRIDE 49
#define NBMAX 128
#define LOG2E 1.44269504f

typedef _Float16 h2_t  __attribute__((ext_vector_type(2)));
typedef _Float16 h8_t  __attribute__((ext_vector_type(8)));
typedef float    f4_t  __attribute__((ext_vector_type(4)));
typedef unsigned int u4_t __attribute__((ext_vector_type(4)));

__device__ __forceinline__ float lrelu(float v) { return v >= 0.f ? v : 0.2f * v; }
__device__ __forceinline__ float eluf(float v)  { return v > 0.f ? v : expm1f(v); }

// acc += (float)lo_half(pk) * w   /   acc += (float)hi_half(pk) * w
#define MIX_LO(acc, pk, w) asm("v_fma_mix_f32 %0, %1, %2, %0 op_sel:[0,0,0] op_sel_hi:[1,0,0]" : "+v"(acc) : "v"(pk), "v"(w))
#define MIX_HI(acc, pk, w) asm("v_fma_mix_f32 %0, %1, %2, %0 op_sel:[1,0,0] op_sel_hi:[1,0,0]" : "+v"(acc) : "v"(pk), "v"(w))

// ---------------- prep: swizzled fp16 B-images ----------------
// W0 image: [ct 0..4][ks 0..3][quad][col][j]  (1280 x 8 half)
// W1 image: [ct 0..3][ks 0..1][quad][col][j]  (512 x 8 half)
__global__ void kPrep(const float* __restrict__ W0,
                      const float* __restrict__ aS0, const float* __restrict__ aD0,
                      const float* __restrict__ W1,
                      __half* __restrict__ W0swz, __half* __restrict__ W1swz)
{
    for (int g = threadIdx.x; g < 1280; g += 256) {
        int col  = g & 15;
        int quad = (g >> 4) & 3;
        int ks   = (g >> 6) & 3;
        int ct   = g >> 8;
        #pragma unroll
        for (int j = 0; j < 8; j++) {
            int k = ks * 32 + quad * 8 + j;
            float v;
            if (ct < 4) {
                v = W0[k * 64 + ct * 16 + col];
            } else {
                int h = col & 7;
                const float* att = (col < 8) ? aS0 : aD0;
                v = 0.f;
                #pragma unroll
                for (int cc = 0; cc < 8; cc++)
                    v += W0[k * 64 + h * 8 + cc] * att[h * 8 + cc];
            }
            W0swz[g * 8 + j] = __float2half(v);
        }
    }
    for (int g = threadIdx.x; g < 512; g += 256) {
        int col  = g & 15;
        int quad = (g >> 4) & 3;
        int ks   = (g >> 6) & 1;
        int ct   = g >> 7;
        #pragma unroll
        for (int j = 0; j < 8; j++) {
            int k = ks * 32 + quad * 8 + j;
            W1swz[g * 8 + j] = __float2half(W1[k * 64 + ct * 16 + col]);
        }
    }
}

// ---------------- tf0 MFMA body: 8 waves/block(512), 16 rows/wave -------------
__device__ __forceinline__ void gemm_body(
    int gb, const float* __restrict__ x, int N,
    __half* __restrict__ xw, float* __restrict__ as, float* __restrict__ ad,
    h8_t* Bl)
{
    int wave = threadIdx.x >> 6, lane = threadIdx.x & 63;
    int row0 = gb * 128 + wave * 16;
    if (row0 >= N) return;
    int quad = lane >> 4, c16 = lane & 15;
    int myrow = min(row0 + c16, N - 1);
    const float* xr = x + (size_t)myrow * 128;
    h8_t a[4];
    #pragma unroll
    for (int ks = 0; ks < 4; ks++) {
        int kb = ks * 32 + quad * 8;
        float4 v0 = *(const float4*)(xr + kb);
        float4 v1 = *(const float4*)(xr + kb + 4);
        h8_t av;
        av[0] = (_Float16)v0.x; av[1] = (_Float16)v0.y;
        av[2] = (_Float16)v0.z; av[3] = (_Float16)v0.w;
        av[4] = (_Float16)v1.x; av[5] = (_Float16)v1.y;
        av[6] = (_Float16)v1.z; av[7] = (_Float16)v1.w;
        a[ks] = av;
    }
    int rbase = row0 + quad * 4;
    #pragma unroll
    for (int ct = 0; ct < 5; ct++) {
        f4_t acc = {0.f, 0.f, 0.f, 0.f};
        #pragma unroll
        for (int ks = 0; ks < 4; ks++) {
            h8_t b = Bl[(ct * 4 + ks) * 64 + lane];
            acc = __builtin_amdgcn_mfma_f32_16x16x32_f16(a[ks], b, acc, 0, 0, 0);
        }
        if (ct < 4) {
            int col = ct * 16 + c16;
            #pragma unroll
            for (int r = 0; r < 4; r++) {
                int row = rbase + r;
                if (row < N) xw[(size_t)row * 64 + col] = __float2half(acc[r]);
            }
        } else {
            #pragma unroll
            for (int r = 0; r < 4; r++) {
                int row = rbase + r;
                if (row < N) {
                    float sc = acc[r] * LOG2E;   // pre-scale logits: exp -> exp2
                    if (c16 < 8) as[(size_t)row * 8 + c16] = sc;
                    else         ad[(size_t)row * 8 + (c16 - 8)] = sc;
                }
            }
        }
    }
}

// ---------------- fused: gemm0 || single-pass binning ----------------
__global__ __launch_bounds__(512, 4) void kGB(
    const float* __restrict__ x, const __half* __restrict__ W0swz, int N,
    __half* __restrict__ xw, float* __restrict__ as, float* __restrict__ ad,
    int gemmBlocks,
    const int* __restrict__ src, const int* __restrict__ dst, int E, int perBlock,
    unsigned* __restrict__ bucketBuf, int* __restrict__ gcur, int NB, int cap,
    int binBlocks)
{
    __shared__ __align__(16) char smem[NBMAX * STRIDE * 4 + NBMAX * 4]; // 25.6 KB union
    int b = blockIdx.x;
    int T = gemmBlocks + binBlocks;
    int lo = (int)((long long)b * gemmBlocks / T);
    int hi = (int)((long long)(b + 1) * gemmBlocks / T);
    if (hi > lo) {
        h8_t* Bl = (h8_t*)smem;
        const float4* s = (const float4*)W0swz;
        float4* d = (float4*)smem;
        for (int i = threadIdx.x; i < 1280; i += 512) d[i] = s[i];
        __syncthreads();
        gemm_body(lo, x, N, xw, as, ad, Bl);
    } else {
        int pb = b - hi;
        unsigned* stage = (unsigned*)smem;
        int* scnt = (int*)(smem + NBMAX * STRIDE * 4);
        int tid = threadIdx.x;
        for (int i = tid; i < NB; i += 512) scnt[i] = 0;
        __syncthreads();
        int e0 = pb * perBlock, e1 = min(E, e0 + perBlock);
        for (int i = e0 + tid; i < e1; i += 512) {
            int d2 = dst[i], s2 = src[i];
            int bk = d2 >> 10;
            unsigned rec = ((unsigned)(d2 & 1023) << 22) | (unsigned)s2;
            int pos = atomicAdd(&scnt[bk], 1);
            if (pos < CAPS) {
                stage[bk * STRIDE + pos] = rec;
            } else {
                int g = atomicAdd(&gcur[bk], 1);
                bucketBuf[(size_t)bk * cap + g] = rec;
            }
        }
        __syncthreads();
        if (tid < NB) {
            int n = min(scnt[tid], CAPS);
            if (n > 0) {
                int gb2 = atomicAdd(&gcur[tid], n);
                unsigned* gp = &bucketBuf[(size_t)tid * cap + gb2];
                for (int j = 0; j < n; j++) gp[j] = stage[tid * STRIDE + j];
            }
        }
    }
}

// ---------------- phase2: per-bucket CSR build ----------------
__global__ __launch_bounds__(256) void kP2(
    const unsigned* __restrict__ bucketBuf, const int* __restrict__ gcur,
    int NB, int cap, int N, int* __restrict__ row, int* __restrict__ adj)
{
    __shared__ int deg[1024];
    __shared__ int curl[1024];
    __shared__ int sc[256];
    int b = blockIdx.x, tid = threadIdx.x;
    int lo = b << 10;
    int hi = min(N, lo + 1024);
    int cnt = hi - lo;
    int size = min(gcur[b], cap);
    sc[tid] = (tid < b) ? gcur[tid] : 0;
    __syncthreads();
    for (int off = 128; off > 0; off >>= 1) {
        if (tid < off) sc[tid] += sc[tid + off];
        __syncthreads();
    }
    int bbase = sc[0];
    __syncthreads();
    for (int i = tid; i < 1024; i += 256) deg[i] = 0;
    __syncthreads();
    const unsigned* buf = bucketBuf + (size_t)b * cap;
    for (int e = tid; e < size; e += 256) atomicAdd(&deg[buf[e] >> 22], 1);
    __syncthreads();
    int dv[4]; int s = 0;
    #pragma unroll
    for (int j = 0; j < 4; j++) { dv[j] = deg[tid * 4 + j]; s += dv[j]; }
    sc[tid] = s; __syncthreads();
    for (int off = 1; off < 256; off <<= 1) {
        int xv = (tid >= off) ? sc[tid - off] : 0;
        __syncthreads();
        sc[tid] += xv;
        __syncthreads();
    }
    int o = (tid ? sc[tid - 1] : 0);
    #pragma unroll
    for (int j = 0; j < 4; j++) {
        int loc = tid * 4 + j;
        curl[loc] = o;
        if (loc < cnt) row[lo + loc] = bbase + o;
        o += dv[j];
    }
    if (b == NB - 1 && tid == 0) row[N] = bbase + size;
    __syncthreads();
    for (int e = tid; e < size; e += 256) {
        unsigned r = buf[e];
        int l = r >> 22;
        int p = atomicAdd(&curl[l], 1);
        adj[bbase + p] = (int)(r & 0x3FFFFF);
    }
}

// ---------------- layer0 aggregation: 2 nodes/wave, unroll x2, fma_mix ------
// wave = 2 halves of 32 lanes; each half owns one node. Within a half:
// e4 = sub>>3 (4 edge slots), hh = sub&7 (head == 16B chunk). Two slot
// groups (A at j+e4, B at j+4+e4) are in flight each iteration.
__global__ __launch_bounds__(256) void k_agg8(
    const __half* __restrict__ xw, const float* __restrict__ as, const float* __restrict__ ad,
    const int* __restrict__ row, const int* __restrict__ adj,
    const float* __restrict__ bias, int N, __half* __restrict__ hbuf)
{
    int n = (blockIdx.x * 256 + threadIdx.x) >> 5;   // 8 nodes per block
    int lane = threadIdx.x & 63;
    int sub  = lane & 31;
    if (n >= N) return;
    int e4 = sub >> 3;
    int hh = sub & 7;
    int rs = row[n], re = row[n + 1];
    const u4_t* xwv = (const u4_t*)xw;               // row stride = 8 chunks
    float adv = ad[(unsigned)n * 8u + hh];
    float shift = lrelu(as[(unsigned)n * 8u + hh] + adv);
    float accv[8];
    #pragma unroll
    for (int k = 0; k < 8; k++) accv[k] = 0.f;
    float dsum = 0.f;

    int j = rs;
    bool vA = j + e4 < re;
    bool vB = j + 4 + e4 < re;
    int  sA = adj[(unsigned)(vA ? j + e4 : rs)];
    int  sB = adj[(unsigned)(vB ? j + 4 + e4 : rs)];
    float eA = lrelu(as[(unsigned)sA * 8u + hh] + adv);
    float eB = lrelu(as[(unsigned)sB * 8u + hh] + adv);
    u4_t xA = xwv[(unsigned)sA * 8u + hh];
    u4_t xB = xwv[(unsigned)sB * 8u + hh];
    for (;;) {
        int jn = j + 8;
        bool vA2 = jn + e4 < re;
        bool vB2 = jn + 4 + e4 < re;
        int  sA2 = adj[(unsigned)(vA2 ? jn + e4 : rs)];
        int  sB2 = adj[(unsigned)(vB2 ? jn + 4 + e4 : rs)];
        float eA2 = lrelu(as[(unsigned)sA2 * 8u + hh] + adv);
        float eB2 = lrelu(as[(unsigned)sB2 * 8u + hh] + adv);
        u4_t xA2 = xwv[(unsigned)sA2 * 8u + hh];
        u4_t xB2 = xwv[(unsigned)sB2 * 8u + hh];
        float wA = vA ? __builtin_amdgcn_exp2f(eA - shift) : 0.f;
        float wB = vB ? __builtin_amdgcn_exp2f(eB - shift) : 0.f;
        dsum += wA + wB;
        #pragma unroll
        for (int q = 0; q < 4; q++) {
            MIX_LO(accv[2 * q],     xA[q], wA);
            MIX_HI(accv[2 * q + 1], xA[q], wA);
        }
        #pragma unroll
        for (int q = 0; q < 4; q++) {
            MIX_LO(accv[2 * q],     xB[q], wB);
            MIX_HI(accv[2 * q + 1], xB[q], wB);
        }
        j = jn;
        vA = vA2; sA = sA2; eA = eA2; xA = xA2;
        vB = vB2; sB = sB2; eB = eB2; xB = xB2;
        if (!__any(vA)) break;   // vB true => vA true (same lane)
    }
    #pragma unroll
    for (int k = 0; k < 8; k++) {
        accv[k] += __shfl_xor(accv[k], 8, 64);
        accv[k] += __shfl_xor(accv[k], 16, 64);
    }
    dsum += __shfl_xor(dsum, 8, 64);
    dsum += __shfl_xor(dsum, 16, 64);
    if (e4 == 0) {
        float inv = 1.f / (1.f + dsum);              // self-loop weight = 1
        h8_t sv = *(const h8_t*)(xw + (size_t)n * 64 + hh * 8);
        float4 b0 = *(const float4*)(bias + hh * 8);
        float4 b1 = *(const float4*)(bias + hh * 8 + 4);
        float bb[8] = {b0.x, b0.y, b0.z, b0.w, b1.x, b1.y, b1.z, b1.w};
        h8_t o;
        #pragma unroll
        for (int k = 0; k < 8; k++) {
            float v = (accv[k] + (float)sv[k]) * inv + bb[k];
            o[k] = (_Float16)eluf(v);
        }
        *(h8_t*)(hbuf + (size_t)n * 64 + hh * 8) = o;
    }
}

// ---------------- layer1 transform: h @ W1 via MFMA (K=64) + as1/ad1 --------
__global__ __launch_bounds__(512, 4) void kTF1(
    const __half* __restrict__ h, const __half* __restrict__ W1swz,
    const float* __restrict__ aS1, const float* __restrict__ aD1, int N,
    __half* __restrict__ hw, float* __restrict__ as1, float* __restrict__ ad1)
{
    __shared__ __align__(16) h8_t Bl[512];
    {
        const float4* s = (const float4*)W1swz;
        float4* d = (float4*)Bl;
        for (int i = threadIdx.x; i < 512; i += 512) d[i] = s[i];
    }
    __syncthreads();
    int wave = threadIdx.x >> 6, lane = threadIdx.x & 63;
    int row0 = blockIdx.x * 128 + wave * 16;
    if (row0 >= N) return;
    int quad = lane >> 4, c16 = lane & 15;
    int myrow = min(row0 + c16, N - 1);
    const __half* hr = h + (size_t)myrow * 64;
    h8_t a0 = *(const h8_t*)(hr + quad * 8);
    h8_t a1 = *(const h8_t*)(hr + 32 + quad * 8);
    int rbase = row0 + quad * 4;
    float ps[4] = {0.f, 0.f, 0.f, 0.f};
    float pd[4] = {0.f, 0.f, 0.f, 0.f};
    #pragma unroll
    for (int ct = 0; ct < 4; ct++) {
        f4_t acc = {0.f, 0.f, 0.f, 0.f};
        acc = __builtin_amdgcn_mfma_f32_16x16x32_f16(a0, Bl[(ct * 2 + 0) * 64 + lane], acc, 0, 0, 0);
        acc = __builtin_amdgcn_mfma_f32_16x16x32_f16(a1, Bl[(ct * 2 + 1) * 64 + lane], acc, 0, 0, 0);
        float s1c = aS1[ct * 16 + c16];
        float d1c = aD1[ct * 16 + c16];
        int col = ct * 16 + c16;
        #pragma unroll
        for (int r = 0; r < 4; r++) {
            int rr = rbase + r;
            if (rr < N) hw[(size_t)rr * 64 + col] = __float2half(acc[r]);
            ps[r] = fmaf(acc[r], s1c, ps[r]);
            pd[r] = fmaf(acc[r], d1c, pd[r]);
        }
    }
    #pragma unroll
    for (int r = 0; r < 4; r++) {
        #pragma unroll
        for (int off = 1; off < 16; off <<= 1) {
            ps[r] += __shfl_xor(ps[r], off, 64);
            pd[r] += __shfl_xor(pd[r], off, 64);
        }
    }
    if (c16 == 0) {
        #pragma unroll
        for (int r = 0; r < 4; r++) {
            int rr = rbase + r;
            if (rr < N) { as1[rr] = ps[r] * LOG2E; ad1[rr] = pd[r] * LOG2E; }
        }
    }
}

// ---------------- layer1 aggregation: 2 nodes/wave, unroll x2, fma_mix ------
__global__ __launch_bounds__(256) void k_agg1(
    const __half* __restrict__ hw, const float* __restrict__ as, const float* __restrict__ ad,
    const int* __restrict__ row, const int* __restrict__ adj,
    const float* __restrict__ bias, int N, float* __restrict__ outp)
{
    int n = (blockIdx.x * 256 + threadIdx.x) >> 5;   // 8 nodes per block
    int lane = threadIdx.x & 63;
    int sub  = lane & 31;
    if (n >= N) return;
    int e4 = sub >> 3;
    int hh = sub & 7;
    int rs = row[n], re = row[n + 1];
    const u4_t* hwv = (const u4_t*)hw;
    float adv = ad[n];
    float shift = lrelu(as[n] + adv);
    float accv[8];
    #pragma unroll
    for (int k = 0; k < 8; k++) accv[k] = 0.f;
    float dsum = 0.f;

    int j = rs;
    bool vA = j + e4 < re;
    bool vB = j + 4 + e4 < re;
    int  sA = adj[(unsigned)(vA ? j + e4 : rs)];
    int  sB = adj[(unsigned)(vB ? j + 4 + e4 : rs)];
    float eA = lrelu(as[(unsigned)sA] + adv);
    float eB = lrelu(as[(unsigned)sB] + adv);
    u4_t xA = hwv[(unsigned)sA * 8u + hh];
    u4_t xB = hwv[(unsigned)sB * 8u + hh];
    for (;;) {
        int jn = j + 8;
        bool vA2 = jn + e4 < re;
        bool vB2 = jn + 4 + e4 < re;
        int  sA2 = adj[(unsigned)(vA2 ? jn + e4 : rs)];
        int  sB2 = adj[(unsigned)(vB2 ? jn + 4 + e4 : rs)];
        float eA2 = lrelu(as[(unsigned)sA2] + adv);
        float eB2 = lrelu(as[(unsigned)sB2] + adv);
        u4_t xA2 = hwv[(unsigned)sA2 * 8u + hh];
        u4_t xB2 = hwv[(unsigned)sB2 * 8u + hh];
        float wA = vA ? __builtin_amdgcn_exp2f(eA - shift) : 0.f;
        float wB = vB ? __builtin_amdgcn_exp2f(eB - shift) : 0.f;
        dsum += wA + wB;
        #pragma unroll
        for (int q = 0; q < 4; q++) {
            MIX_LO(accv[2 * q],     xA[q], wA);
            MIX_HI(accv[2 * q + 1], xA[q], wA);
        }
        #pragma unroll
        for (int q = 0; q < 4; q++) {
            MIX_LO(accv[2 * q],     xB[q], wB);
            MIX_HI(accv[2 * q + 1], xB[q], wB);
        }
        j = jn;
        vA = vA2; sA = sA2; eA = eA2; xA = xA2;
        vB = vB2; sB = sB2; eB = eB2; xB = xB2;
        if (!__any(vA)) break;
    }
    #pragma unroll
    for (int k = 0; k < 8; k++) {
        accv[k] += __shfl_xor(accv[k], 8, 64);
        accv[k] += __shfl_xor(accv[k], 16, 64);
    }
    dsum += __shfl_xor(dsum, 8, 64);
    dsum += __shfl_xor(dsum, 16, 64);
    if (e4 == 0) {
        float inv = 1.f / (1.f + dsum);
        h8_t sv = *(const h8_t*)(hw + (size_t)n * 64 + hh * 8);
        float4 b0 = *(const float4*)(bias + hh * 8);
        float4 b1 = *(const float4*)(bias + hh * 8 + 4);
        float bb[8] = {b0.x, b0.y, b0.z, b0.w, b1.x, b1.y, b1.z, b1.w};
        float ov[8];
        #pragma unroll
        for (int k = 0; k < 8; k++)
            ov[k] = eluf((accv[k] + (float)sv[k]) * inv + bb[k]);
        float4 o0 = {ov[0], ov[1], ov[2], ov[3]};
        float4 o1 = {ov[4], ov[5], ov[6], ov[7]};
        float4* op = (float4*)(outp + (size_t)n * 64 + hh * 8);
        op[0] = o0;
        op[1] = o1;
    }
}

extern "C" void kernel_launch(void* const* d_in, const int* in_sizes, int n_in,
                              void* d_out, int out_size, void* d_ws, size_t ws_size,
                              hipStream_t stream)
{
    const float* x   = (const float*)d_in[0];
    const int*   ei  = (const int*)d_in[1];
    const float* W0  = (const float*)d_in[2];
    const float* aS0 = (const float*)d_in[3];
    const float* aD0 = (const float*)d_in[4];
    const float* b0  = (const float*)d_in[5];
    const float* W1  = (const float*)d_in[6];
    const float* aS1 = (const float*)d_in[7];
    const float* aD1 = (const float*)d_in[8];
    const float* b1  = (const float*)d_in[9];

    const int N = in_sizes[0] / 128;
    const int E = in_sizes[1] / 2;
    const int* srcp = ei;
    const int* dstp = ei + E;

    const int NB  = (N + 1023) >> 10;
    const int cap = E / NB + 4096;

    char* ws = (char*)d_ws;
    size_t off = 0;
    auto alloc = [&](size_t bytes) -> size_t {
        size_t o = off;
        off = (o + bytes + 255) & ~(size_t)255;
        return o;
    };
    __half* B1 = (__half*)(ws + alloc((size_t)N * 64 * 2));     // xw (half); later reused as hw
    size_t b2Bytes = (size_t)N * 64 * 2;
    size_t bkBytes = (size_t)NB * cap * 4;
    char*  region  = ws + alloc(b2Bytes > bkBytes ? b2Bytes : bkBytes);
    __half*   B2        = (__half*)region;     // h overlays bucketBuf (dead after kP2)
    unsigned* bucketBuf = (unsigned*)region;
    float* as0 = (float*)(ws + alloc((size_t)N * 8 * 4));
    float* ad0 = (float*)(ws + alloc((size_t)N * 8 * 4));
    float* as1 = (float*)(ws + alloc((size_t)N * 4));
    float* ad1 = (float*)(ws + alloc((size_t)N * 4));
    int*   row = (int*)(ws + alloc((size_t)(N + 1) * 4));
    int*   adj = (int*)(ws + alloc((size_t)E * 4));
    int*  gcur = (int*)(ws + alloc((size_t)NB * 4));
    __half* W0swz = (__half*)(ws + alloc(1280 * 8 * 2));
    __half* W1swz = (__half*)(ws + alloc(512 * 8 * 2));

    const int gemmBlocks = (N + 127) / 128;
    const int binBlocks  = 1024;
    const int perBlock   = (E + binBlocks - 1) / binBlocks;

    hipMemsetAsync(gcur, 0, (size_t)NB * 4, stream);
    kPrep<<<1, 256, 0, stream>>>(W0, aS0, aD0, W1, W0swz, W1swz);
    kGB<<<gemmBlocks + binBlocks, 512, 0, stream>>>(
        x, W0swz, N, B1, as0, ad0, gemmBlocks,
        srcp, dstp, E, perBlock, bucketBuf, gcur, NB, cap, binBlocks);
    kP2<<<NB, 256, 0, stream>>>(bucketBuf, gcur, NB, cap, N, row, adj);

    const int agBlocks = (N + 7) / 8;   // 8 nodes per 256-thread block
    // layer-0 aggregation: reads xw (B1), writes h (B2, over dead bucketBuf)
    k_agg8<<<agBlocks, 256, 0, stream>>>(B1, as0, ad0, row, adj, b0, N, B2);
    // layer-1 transform: reads h (B2), writes hw into B1 (xw dead) + as1/ad1
    kTF1<<<(N + 127) / 128, 512, 0, stream>>>(B2, W1swz, aS1, aD1, N, B1, as1, ad1);
    // layer-1 aggregation
    k_agg1<<<agBlocks, 256, 0, stream>>>(B1, as1, ad1, row, adj, b1, N, (float*)d_out);
}

// Round 6
// 264.827 us; speedup vs baseline: 1.2788x; 1.0806x over previous
//
#include <hip/hip_runtime.h>
#include <hip/hip_fp16.h>
#include <math.h>

// GAT 2-layer. R19 = R17 + fault-proofing (container failed twice on R17/R18;
// closing the only two OOB-read/write hazards so a third failure proves infra).
// (1) agg kernels: depth-2 software pipeline — 2-phase manual unroll, adj
// prefetched two iterations ahead, gathers one ahead. Masked adj reads now
// fall back to index 0 (always valid; rs could equal E for a zero-in-degree
// tail node). (2) kP2 parallelism: 256-node buckets (NB=391 blocks vs 98).
// bucketBuf writes clamped to cap (reads already min(gcur,cap)).

#define CAPS 16
#define STRIDE 17
#define NBMAX 512
#define LOG2E 1.44269504f

typedef _Float16 h2_t  __attribute__((ext_vector_type(2)));
typedef _Float16 h8_t  __attribute__((ext_vector_type(8)));
typedef float    f4_t  __attribute__((ext_vector_type(4)));
typedef unsigned int u4_t __attribute__((ext_vector_type(4)));

__device__ __forceinline__ float lrelu(float v) { return v >= 0.f ? v : 0.2f * v; }
__device__ __forceinline__ float eluf(float v)  { return v > 0.f ? v : expm1f(v); }

// acc += (float)lo_half(pk) * w   /   acc += (float)hi_half(pk) * w
#define MIX_LO(acc, pk, w) asm("v_fma_mix_f32 %0, %1, %2, %0 op_sel:[0,0,0] op_sel_hi:[1,0,0]" : "+v"(acc) : "v"(pk), "v"(w))
#define MIX_HI(acc, pk, w) asm("v_fma_mix_f32 %0, %1, %2, %0 op_sel:[1,0,0] op_sel_hi:[1,0,0]" : "+v"(acc) : "v"(pk), "v"(w))

// ---------------- prep: swizzled fp16 B-images ----------------
// W0 image: [ct 0..4][ks 0..3][quad][col][j]  (1280 x 8 half)
// W1 image: [ct 0..3][ks 0..1][quad][col][j]  (512 x 8 half)
__global__ void kPrep(const float* __restrict__ W0,
                      const float* __restrict__ aS0, const float* __restrict__ aD0,
                      const float* __restrict__ W1,
                      __half* __restrict__ W0swz, __half* __restrict__ W1swz)
{
    for (int g = threadIdx.x; g < 1280; g += 256) {
        int col  = g & 15;
        int quad = (g >> 4) & 3;
        int ks   = (g >> 6) & 3;
        int ct   = g >> 8;
        #pragma unroll
        for (int j = 0; j < 8; j++) {
            int k = ks * 32 + quad * 8 + j;
            float v;
            if (ct < 4) {
                v = W0[k * 64 + ct * 16 + col];
            } else {
                int h = col & 7;
                const float* att = (col < 8) ? aS0 : aD0;
                v = 0.f;
                #pragma unroll
                for (int cc = 0; cc < 8; cc++)
                    v += W0[k * 64 + h * 8 + cc] * att[h * 8 + cc];
            }
            W0swz[g * 8 + j] = __float2half(v);
        }
    }
    for (int g = threadIdx.x; g < 512; g += 256) {
        int col  = g & 15;
        int quad = (g >> 4) & 3;
        int ks   = (g >> 6) & 1;
        int ct   = g >> 7;
        #pragma unroll
        for (int j = 0; j < 8; j++) {
            int k = ks * 32 + quad * 8 + j;
            W1swz[g * 8 + j] = __float2half(W1[k * 64 + ct * 16 + col]);
        }
    }
}

// ---------------- tf0 MFMA body: 8 waves/block(512), 16 rows/wave -------------
__device__ __forceinline__ void gemm_body(
    int gb, const float* __restrict__ x, int N,
    __half* __restrict__ xw, float* __restrict__ as, float* __restrict__ ad,
    h8_t* Bl)
{
    int wave = threadIdx.x >> 6, lane = threadIdx.x & 63;
    int row0 = gb * 128 + wave * 16;
    if (row0 >= N) return;
    int quad = lane >> 4, c16 = lane & 15;
    int myrow = min(row0 + c16, N - 1);
    const float* xr = x + (size_t)myrow * 128;
    h8_t a[4];
    #pragma unroll
    for (int ks = 0; ks < 4; ks++) {
        int kb = ks * 32 + quad * 8;
        float4 v0 = *(const float4*)(xr + kb);
        float4 v1 = *(const float4*)(xr + kb + 4);
        h8_t av;
        av[0] = (_Float16)v0.x; av[1] = (_Float16)v0.y;
        av[2] = (_Float16)v0.z; av[3] = (_Float16)v0.w;
        av[4] = (_Float16)v1.x; av[5] = (_Float16)v1.y;
        av[6] = (_Float16)v1.z; av[7] = (_Float16)v1.w;
        a[ks] = av;
    }
    int rbase = row0 + quad * 4;
    #pragma unroll
    for (int ct = 0; ct < 5; ct++) {
        f4_t acc = {0.f, 0.f, 0.f, 0.f};
        #pragma unroll
        for (int ks = 0; ks < 4; ks++) {
            h8_t b = Bl[(ct * 4 + ks) * 64 + lane];
            acc = __builtin_amdgcn_mfma_f32_16x16x32_f16(a[ks], b, acc, 0, 0, 0);
        }
        if (ct < 4) {
            int col = ct * 16 + c16;
            #pragma unroll
            for (int r = 0; r < 4; r++) {
                int row = rbase + r;
                if (row < N) xw[(size_t)row * 64 + col] = __float2half(acc[r]);
            }
        } else {
            #pragma unroll
            for (int r = 0; r < 4; r++) {
                int row = rbase + r;
                if (row < N) {
                    float sc = acc[r] * LOG2E;   // pre-scale logits: exp -> exp2
                    if (c16 < 8) as[(size_t)row * 8 + c16] = sc;
                    else         ad[(size_t)row * 8 + (c16 - 8)] = sc;
                }
            }
        }
    }
}

// ---------------- fused: gemm0 || single-pass binning ----------------
__global__ __launch_bounds__(512, 4) void kGB(
    const float* __restrict__ x, const __half* __restrict__ W0swz, int N,
    __half* __restrict__ xw, float* __restrict__ as, float* __restrict__ ad,
    int gemmBlocks,
    const int* __restrict__ src, const int* __restrict__ dst, int E, int perBlock,
    unsigned* __restrict__ bucketBuf, int* __restrict__ gcur, int NB, int cap,
    int binBlocks)
{
    __shared__ __align__(16) char smem[NBMAX * STRIDE * 4 + NBMAX * 4]; // 36.9 KB union
    int b = blockIdx.x;
    int T = gemmBlocks + binBlocks;
    int lo = (int)((long long)b * gemmBlocks / T);
    int hi = (int)((long long)(b + 1) * gemmBlocks / T);
    if (hi > lo) {
        h8_t* Bl = (h8_t*)smem;
        const float4* s = (const float4*)W0swz;
        float4* d = (float4*)smem;
        for (int i = threadIdx.x; i < 1280; i += 512) d[i] = s[i];
        __syncthreads();
        gemm_body(lo, x, N, xw, as, ad, Bl);
    } else {
        int pb = b - hi;
        unsigned* stage = (unsigned*)smem;
        int* scnt = (int*)(smem + NBMAX * STRIDE * 4);
        int tid = threadIdx.x;
        for (int i = tid; i < NB; i += 512) scnt[i] = 0;
        __syncthreads();
        int e0 = pb * perBlock, e1 = min(E, e0 + perBlock);
        for (int i = e0 + tid; i < e1; i += 512) {
            int d2 = dst[i], s2 = src[i];
            int bk = d2 >> 8;                              // 256-node buckets
            unsigned rec = ((unsigned)(d2 & 255) << 22) | (unsigned)s2;
            int pos = atomicAdd(&scnt[bk], 1);
            if (pos < CAPS) {
                stage[bk * STRIDE + pos] = rec;
            } else {
                int g = atomicAdd(&gcur[bk], 1);
                if (g < cap) bucketBuf[(size_t)bk * cap + g] = rec;
            }
        }
        __syncthreads();
        for (int t = tid; t < NB; t += 512) {
            int n = min(scnt[t], CAPS);
            if (n > 0) {
                int gb2 = atomicAdd(&gcur[t], n);
                unsigned* gp = &bucketBuf[(size_t)t * cap + gb2];
                for (int j = 0; j < n; j++)
                    if (gb2 + j < cap) gp[j] = stage[t * STRIDE + j];
            }
        }
    }
}

// ---------------- phase2: per-bucket CSR build (256-node buckets) ----------
__global__ __launch_bounds__(256) void kP2(
    const unsigned* __restrict__ bucketBuf, const int* __restrict__ gcur,
    int NB, int cap, int N, int* __restrict__ row, int* __restrict__ adj)
{
    __shared__ int deg[256];
    __shared__ int curl[256];
    __shared__ int sc[256];
    int b = blockIdx.x, tid = threadIdx.x;
    int lo = b << 8;
    int hi = min(N, lo + 256);
    int cnt = hi - lo;
    int size = min(gcur[b], cap);
    int part = 0;
    for (int i = tid; i < b; i += 256) part += min(gcur[i], cap);
    sc[tid] = part;
    __syncthreads();
    for (int off = 128; off > 0; off >>= 1) {
        if (tid < off) sc[tid] += sc[tid + off];
        __syncthreads();
    }
    int bbase = sc[0];
    __syncthreads();
    deg[tid] = 0;
    __syncthreads();
    const unsigned* buf = bucketBuf + (size_t)b * cap;
    for (int e = tid; e < size; e += 256) atomicAdd(&deg[buf[e] >> 22], 1);
    __syncthreads();
    int d = deg[tid];
    sc[tid] = d;
    __syncthreads();
    for (int off = 1; off < 256; off <<= 1) {
        int xv = (tid >= off) ? sc[tid - off] : 0;
        __syncthreads();
        sc[tid] += xv;
        __syncthreads();
    }
    int o = (tid ? sc[tid - 1] : 0);
    curl[tid] = o;
    if (tid < cnt) row[lo + tid] = bbase + o;
    if (b == NB - 1 && tid == 0) row[N] = bbase + size;
    __syncthreads();
    for (int e = tid; e < size; e += 256) {
        unsigned r = buf[e];
        int l = r >> 22;
        int p = atomicAdd(&curl[l], 1);
        adj[bbase + p] = (int)(r & 0x3FFFFF);
    }
}

// ---------------- layer0 aggregation: 2 nodes/wave, depth-2 pipeline --------
// wave = 2 halves of 32 lanes; each half owns one node. Within a half:
// e4 = sub>>3 (4 edge slots), hh = sub&7 (head == 16B chunk).
// 2-phase manual unroll: adj prefetched 2 iters ahead, gathers 1 ahead —
// every load has a full iteration of issue between it and its use.
// Masked adj reads fall back to index 0 (always valid).
__global__ __launch_bounds__(256) void k_agg8(
    const __half* __restrict__ xw, const float* __restrict__ as, const float* __restrict__ ad,
    const int* __restrict__ row, const int* __restrict__ adj,
    const float* __restrict__ bias, int N, __half* __restrict__ hbuf)
{
    int n = (blockIdx.x * 256 + threadIdx.x) >> 5;   // 8 nodes per block
    int lane = threadIdx.x & 63;
    int sub  = lane & 31;
    if (n >= N) return;
    int e4 = sub >> 3;
    int hh = sub & 7;
    int rs = row[n], re = row[n + 1];
    const u4_t* xwv = (const u4_t*)xw;               // row stride = 8 chunks
    float adv = ad[(unsigned)n * 8u + hh];
    float shift = lrelu(as[(unsigned)n * 8u + hh] + adv);
    float accv[8];
    #pragma unroll
    for (int k = 0; k < 8; k++) accv[k] = 0.f;
    float dsum = 0.f;

    int j = rs;
    bool vA0 = j + e4 < re,      vB0 = j + 4 + e4 < re;
    int  sA0 = adj[(unsigned)(vA0 ? j + e4 : 0)];
    int  sB0 = adj[(unsigned)(vB0 ? j + 4 + e4 : 0)];
    bool vA1 = j + 8 + e4 < re,  vB1 = j + 12 + e4 < re;
    int  sA1 = adj[(unsigned)(vA1 ? j + 8 + e4 : 0)];
    int  sB1 = adj[(unsigned)(vB1 ? j + 12 + e4 : 0)];
    float eA0 = lrelu(as[(unsigned)sA0 * 8u + hh] + adv);
    float eB0 = lrelu(as[(unsigned)sB0 * 8u + hh] + adv);
    u4_t xA0 = xwv[(unsigned)sA0 * 8u + hh];
    u4_t xB0 = xwv[(unsigned)sB0 * 8u + hh];
    float eA1, eB1; u4_t xA1, xB1;

    for (;;) {
        // phase even: prefetch adj(j+16)->slot0, gathers slot1, compute slot0
        {
            bool vA2 = j + 16 + e4 < re, vB2 = j + 20 + e4 < re;
            int nsA = adj[(unsigned)(vA2 ? j + 16 + e4 : 0)];
            int nsB = adj[(unsigned)(vB2 ? j + 20 + e4 : 0)];
            eA1 = lrelu(as[(unsigned)sA1 * 8u + hh] + adv);
            eB1 = lrelu(as[(unsigned)sB1 * 8u + hh] + adv);
            xA1 = xwv[(unsigned)sA1 * 8u + hh];
            xB1 = xwv[(unsigned)sB1 * 8u + hh];
            float wA = vA0 ? __builtin_amdgcn_exp2f(eA0 - shift) : 0.f;
            float wB = vB0 ? __builtin_amdgcn_exp2f(eB0 - shift) : 0.f;
            dsum += wA + wB;
            #pragma unroll
            for (int q = 0; q < 4; q++) {
                MIX_LO(accv[2 * q],     xA0[q], wA);
                MIX_HI(accv[2 * q + 1], xA0[q], wA);
            }
            #pragma unroll
            for (int q = 0; q < 4; q++) {
                MIX_LO(accv[2 * q],     xB0[q], wB);
                MIX_HI(accv[2 * q + 1], xB0[q], wB);
            }
            vA0 = vA2; vB0 = vB2; sA0 = nsA; sB0 = nsB;
        }
        j += 8;
        if (!__any(vA1)) break;
        // phase odd: prefetch adj(j+16)->slot1, gathers slot0, compute slot1
        {
            bool vA2 = j + 16 + e4 < re, vB2 = j + 20 + e4 < re;
            int nsA = adj[(unsigned)(vA2 ? j + 16 + e4 : 0)];
            int nsB = adj[(unsigned)(vB2 ? j + 20 + e4 : 0)];
            eA0 = lrelu(as[(unsigned)sA0 * 8u + hh] + adv);
            eB0 = lrelu(as[(unsigned)sB0 * 8u + hh] + adv);
            xA0 = xwv[(unsigned)sA0 * 8u + hh];
            xB0 = xwv[(unsigned)sB0 * 8u + hh];
            float wA = vA1 ? __builtin_amdgcn_exp2f(eA1 - shift) : 0.f;
            float wB = vB1 ? __builtin_amdgcn_exp2f(eB1 - shift) : 0.f;
            dsum += wA + wB;
            #pragma unroll
            for (int q = 0; q < 4; q++) {
                MIX_LO(accv[2 * q],     xA1[q], wA);
                MIX_HI(accv[2 * q + 1], xA1[q], wA);
            }
            #pragma unroll
            for (int q = 0; q < 4; q++) {
                MIX_LO(accv[2 * q],     xB1[q], wB);
                MIX_HI(accv[2 * q + 1], xB1[q], wB);
            }
            vA1 = vA2; vB1 = vB2; sA1 = nsA; sB1 = nsB;
        }
        j += 8;
        if (!__any(vA0)) break;
    }
    #pragma unroll
    for (int k = 0; k < 8; k++) {
        accv[k] += __shfl_xor(accv[k], 8, 64);
        accv[k] += __shfl_xor(accv[k], 16, 64);
    }
    dsum += __shfl_xor(dsum, 8, 64);
    dsum += __shfl_xor(dsum, 16, 64);
    if (e4 == 0) {
        float inv = 1.f / (1.f + dsum);              // self-loop weight = 1
        h8_t sv = *(const h8_t*)(xw + (size_t)n * 64 + hh * 8);
        float4 b0 = *(const float4*)(bias + hh * 8);
        float4 b1 = *(const float4*)(bias + hh * 8 + 4);
        float bb[8] = {b0.x, b0.y, b0.z, b0.w, b1.x, b1.y, b1.z, b1.w};
        h8_t o;
        #pragma unroll
        for (int k = 0; k < 8; k++) {
            float v = (accv[k] + (float)sv[k]) * inv + bb[k];
            o[k] = (_Float16)eluf(v);
        }
        *(h8_t*)(hbuf + (size_t)n * 64 + hh * 8) = o;
    }
}

// ---------------- layer1 transform: h @ W1 via MFMA (K=64) + as1/ad1 --------
__global__ __launch_bounds__(512, 4) void kTF1(
    const __half* __restrict__ h, const __half* __restrict__ W1swz,
    const float* __restrict__ aS1, const float* __restrict__ aD1, int N,
    __half* __restrict__ hw, float* __restrict__ as1, float* __restrict__ ad1)
{
    __shared__ __align__(16) h8_t Bl[512];
    {
        const float4* s = (const float4*)W1swz;
        float4* d = (float4*)Bl;
        for (int i = threadIdx.x; i < 512; i += 512) d[i] = s[i];
    }
    __syncthreads();
    int wave = threadIdx.x >> 6, lane = threadIdx.x & 63;
    int row0 = blockIdx.x * 128 + wave * 16;
    if (row0 >= N) return;
    int quad = lane >> 4, c16 = lane & 15;
    int myrow = min(row0 + c16, N - 1);
    const __half* hr = h + (size_t)myrow * 64;
    h8_t a0 = *(const h8_t*)(hr + quad * 8);
    h8_t a1 = *(const h8_t*)(hr + 32 + quad * 8);
    int rbase = row0 + quad * 4;
    float ps[4] = {0.f, 0.f, 0.f, 0.f};
    float pd[4] = {0.f, 0.f, 0.f, 0.f};
    #pragma unroll
    for (int ct = 0; ct < 4; ct++) {
        f4_t acc = {0.f, 0.f, 0.f, 0.f};
        acc = __builtin_amdgcn_mfma_f32_16x16x32_f16(a0, Bl[(ct * 2 + 0) * 64 + lane], acc, 0, 0, 0);
        acc = __builtin_amdgcn_mfma_f32_16x16x32_f16(a1, Bl[(ct * 2 + 1) * 64 + lane], acc, 0, 0, 0);
        float s1c = aS1[ct * 16 + c16];
        float d1c = aD1[ct * 16 + c16];
        int col = ct * 16 + c16;
        #pragma unroll
        for (int r = 0; r < 4; r++) {
            int rr = rbase + r;
            if (rr < N) hw[(size_t)rr * 64 + col] = __float2half(acc[r]);
            ps[r] = fmaf(acc[r], s1c, ps[r]);
            pd[r] = fmaf(acc[r], d1c, pd[r]);
        }
    }
    #pragma unroll
    for (int r = 0; r < 4; r++) {
        #pragma unroll
        for (int off = 1; off < 16; off <<= 1) {
            ps[r] += __shfl_xor(ps[r], off, 64);
            pd[r] += __shfl_xor(pd[r], off, 64);
        }
    }
    if (c16 == 0) {
        #pragma unroll
        for (int r = 0; r < 4; r++) {
            int rr = rbase + r;
            if (rr < N) { as1[rr] = ps[r] * LOG2E; ad1[rr] = pd[r] * LOG2E; }
        }
    }
}

// ---------------- layer1 aggregation: 2 nodes/wave, depth-2 pipeline --------
__global__ __launch_bounds__(256) void k_agg1(
    const __half* __restrict__ hw, const float* __restrict__ as, const float* __restrict__ ad,
    const int* __restrict__ row, const int* __restrict__ adj,
    const float* __restrict__ bias, int N, float* __restrict__ outp)
{
    int n = (blockIdx.x * 256 + threadIdx.x) >> 5;   // 8 nodes per block
    int lane = threadIdx.x & 63;
    int sub  = lane & 31;
    if (n >= N) return;
    int e4 = sub >> 3;
    int hh = sub & 7;
    int rs = row[n], re = row[n + 1];
    const u4_t* hwv = (const u4_t*)hw;
    float adv = ad[n];
    float shift = lrelu(as[n] + adv);
    float accv[8];
    #pragma unroll
    for (int k = 0; k < 8; k++) accv[k] = 0.f;
    float dsum = 0.f;

    int j = rs;
    bool vA0 = j + e4 < re,      vB0 = j + 4 + e4 < re;
    int  sA0 = adj[(unsigned)(vA0 ? j + e4 : 0)];
    int  sB0 = adj[(unsigned)(vB0 ? j + 4 + e4 : 0)];
    bool vA1 = j + 8 + e4 < re,  vB1 = j + 12 + e4 < re;
    int  sA1 = adj[(unsigned)(vA1 ? j + 8 + e4 : 0)];
    int  sB1 = adj[(unsigned)(vB1 ? j + 12 + e4 : 0)];
    float eA0 = lrelu(as[(unsigned)sA0] + adv);
    float eB0 = lrelu(as[(unsigned)sB0] + adv);
    u4_t xA0 = hwv[(unsigned)sA0 * 8u + hh];
    u4_t xB0 = hwv[(unsigned)sB0 * 8u + hh];
    float eA1, eB1; u4_t xA1, xB1;

    for (;;) {
        // phase even
        {
            bool vA2 = j + 16 + e4 < re, vB2 = j + 20 + e4 < re;
            int nsA = adj[(unsigned)(vA2 ? j + 16 + e4 : 0)];
            int nsB = adj[(unsigned)(vB2 ? j + 20 + e4 : 0)];
            eA1 = lrelu(as[(unsigned)sA1] + adv);
            eB1 = lrelu(as[(unsigned)sB1] + adv);
            xA1 = hwv[(unsigned)sA1 * 8u + hh];
            xB1 = hwv[(unsigned)sB1 * 8u + hh];
            float wA = vA0 ? __builtin_amdgcn_exp2f(eA0 - shift) : 0.f;
            float wB = vB0 ? __builtin_amdgcn_exp2f(eB0 - shift) : 0.f;
            dsum += wA + wB;
            #pragma unroll
            for (int q = 0; q < 4; q++) {
                MIX_LO(accv[2 * q],     xA0[q], wA);
                MIX_HI(accv[2 * q + 1], xA0[q], wA);
            }
            #pragma unroll
            for (int q = 0; q < 4; q++) {
                MIX_LO(accv[2 * q],     xB0[q], wB);
                MIX_HI(accv[2 * q + 1], xB0[q], wB);
            }
            vA0 = vA2; vB0 = vB2; sA0 = nsA; sB0 = nsB;
        }
        j += 8;
        if (!__any(vA1)) break;
        // phase odd
        {
            bool vA2 = j + 16 + e4 < re, vB2 = j + 20 + e4 < re;
            int nsA = adj[(unsigned)(vA2 ? j + 16 + e4 : 0)];
            int nsB = adj[(unsigned)(vB2 ? j + 20 + e4 : 0)];
            eA0 = lrelu(as[(unsigned)sA0] + adv);
            eB0 = lrelu(as[(unsigned)sB0] + adv);
            xA0 = hwv[(unsigned)sA0 * 8u + hh];
            xB0 = hwv[(unsigned)sB0 * 8u + hh];
            float wA = vA1 ? __builtin_amdgcn_exp2f(eA1 - shift) : 0.f;
            float wB = vB1 ? __builtin_amdgcn_exp2f(eB1 - shift) : 0.f;
            dsum += wA + wB;
            #pragma unroll
            for (int q = 0; q < 4; q++) {
                MIX_LO(accv[2 * q],     xA1[q], wA);
                MIX_HI(accv[2 * q + 1], xA1[q], wA);
            }
            #pragma unroll
            for (int q = 0; q < 4; q++) {
                MIX_LO(accv[2 * q],     xB1[q], wB);
                MIX_HI(accv[2 * q + 1], xB1[q], wB);
            }
            vA1 = vA2; vB1 = vB2; sA1 = nsA; sB1 = nsB;
        }
        j += 8;
        if (!__any(vA0)) break;
    }
    #pragma unroll
    for (int k = 0; k < 8; k++) {
        accv[k] += __shfl_xor(accv[k], 8, 64);
        accv[k] += __shfl_xor(accv[k], 16, 64);
    }
    dsum += __shfl_xor(dsum, 8, 64);
    dsum += __shfl_xor(dsum, 16, 64);
    if (e4 == 0) {
        float inv = 1.f / (1.f + dsum);
        h8_t sv = *(const h8_t*)(hw + (size_t)n * 64 + hh * 8);
        float4 b0 = *(const float4*)(bias + hh * 8);
        float4 b1 = *(const float4*)(bias + hh * 8 + 4);
        float bb[8] = {b0.x, b0.y, b0.z, b0.w, b1.x, b1.y, b1.z, b1.w};
        float ov[8];
        #pragma unroll
        for (int k = 0; k < 8; k++)
            ov[k] = eluf((accv[k] + (float)sv[k]) * inv + bb[k]);
        float4 o0 = {ov[0], ov[1], ov[2], ov[3]};
        float4 o1 = {ov[4], ov[5], ov[6], ov[7]};
        float4* op = (float4*)(outp + (size_t)n * 64 + hh * 8);
        op[0] = o0;
        op[1] = o1;
    }
}

extern "C" void kernel_launch(void* const* d_in, const int* in_sizes, int n_in,
                              void* d_out, int out_size, void* d_ws, size_t ws_size,
                              hipStream_t stream)
{
    const float* x   = (const float*)d_in[0];
    const int*   ei  = (const int*)d_in[1];
    const float* W0  = (const float*)d_in[2];
    const float* aS0 = (const float*)d_in[3];
    const float* aD0 = (const float*)d_in[4];
    const float* b0  = (const float*)d_in[5];
    const float* W1  = (const float*)d_in[6];
    const float* aS1 = (const float*)d_in[7];
    const float* aD1 = (const float*)d_in[8];
    const float* b1  = (const float*)d_in[9];

    const int N = in_sizes[0] / 128;
    const int E = in_sizes[1] / 2;
    const int* srcp = ei;
    const int* dstp = ei + E;

    const int NB  = (N + 255) >> 8;          // 256-node buckets
    const int cap = E / NB + 4096;

    char* ws = (char*)d_ws;
    size_t off = 0;
    auto alloc = [&](size_t bytes) -> size_t {
        size_t o = off;
        off = (o + bytes + 255) & ~(size_t)255;
        return o;
    };
    __half* B1 = (__half*)(ws + alloc((size_t)N * 64 * 2));     // xw (half); later reused as hw
    size_t b2Bytes = (size_t)N * 64 * 2;
    size_t bkBytes = (size_t)NB * cap * 4;
    char*  region  = ws + alloc(b2Bytes > bkBytes ? b2Bytes : bkBytes);
    __half*   B2        = (__half*)region;     // h overlays bucketBuf (dead after kP2)
    unsigned* bucketBuf = (unsigned*)region;
    float* as0 = (float*)(ws + alloc((size_t)N * 8 * 4));
    float* ad0 = (float*)(ws + alloc((size_t)N * 8 * 4));
    float* as1 = (float*)(ws + alloc((size_t)N * 4));
    float* ad1 = (float*)(ws + alloc((size_t)N * 4));
    int*   row = (int*)(ws + alloc((size_t)(N + 1) * 4));
    int*   adj = (int*)(ws + alloc((size_t)E * 4));
    int*  gcur = (int*)(ws + alloc((size_t)NB * 4));
    __half* W0swz = (__half*)(ws + alloc(1280 * 8 * 2));
    __half* W1swz = (__half*)(ws + alloc(512 * 8 * 2));

    const int gemmBlocks = (N + 127) / 128;
    const int binBlocks  = 1024;
    const int perBlock   = (E + binBlocks - 1) / binBlocks;

    hipMemsetAsync(gcur, 0, (size_t)NB * 4, stream);
    kPrep<<<1, 256, 0, stream>>>(W0, aS0, aD0, W1, W0swz, W1swz);
    kGB<<<gemmBlocks + binBlocks, 512, 0, stream>>>(
        x, W0swz, N, B1, as0, ad0, gemmBlocks,
        srcp, dstp, E, perBlock, bucketBuf, gcur, NB, cap, binBlocks);
    kP2<<<NB, 256, 0, stream>>>(bucketBuf, gcur, NB, cap, N, row, adj);

    const int agBlocks = (N + 7) / 8;   // 8 nodes per 256-thread block
    // layer-0 aggregation: reads xw (B1), writes h (B2, over dead bucketBuf)
    k_agg8<<<agBlocks, 256, 0, stream>>>(B1, as0, ad0, row, adj, b0, N, B2);
    // layer-1 transform: reads h (B2), writes hw into B1 (xw dead) + as1/ad1
    kTF1<<<(N + 127) / 128, 512, 0, stream>>>(B2, W1swz, aS1, aD1, N, B1, as1, ad1);
    // layer-1 aggregation
    k_agg1<<<agBlocks, 256, 0, stream>>>(B1, as1, ad1, row, adj, b1, N, (float*)d_out);
}

// Round 7
// 245.232 us; speedup vs baseline: 1.3810x; 1.0799x over previous
//
#include <hip/hip_runtime.h>
#include <hip/hip_fp16.h>
#include <math.h>

// GAT 2-layer. R20: (1) kPrep eliminated — its <<<1,256>>> launch serialized
// the GPU; kGB gemm blocks and kTF1 now build their swizzled LDS weight
// images directly from W0/W1 (L2-broadcast reads, trivial aggregate cost).
// (2) binBlocks 1024->512: halves the 400K contended flush atomics on gcur
// and per-block fixed costs. (3) agg epilogues: expm1f -> exp2-based ELU
// (one v_exp_f32 instead of a libcall chain). Agg kernels are at their
// random-gather BW ceiling (~3.3 TB/s observed asymptote) — left as-is.

#define CAPS 16
#define STRIDE 17
#define NBMAX 512
#define LOG2E 1.44269504f

typedef _Float16 h2_t  __attribute__((ext_vector_type(2)));
typedef _Float16 h8_t  __attribute__((ext_vector_type(8)));
typedef float    f4_t  __attribute__((ext_vector_type(4)));
typedef unsigned int u4_t __attribute__((ext_vector_type(4)));

__device__ __forceinline__ float lrelu(float v) { return v >= 0.f ? v : 0.2f * v; }
__device__ __forceinline__ float eluf(float v)  {
    return v > 0.f ? v : __builtin_amdgcn_exp2f(v * LOG2E) - 1.f;
}

// acc += (float)lo_half(pk) * w   /   acc += (float)hi_half(pk) * w
#define MIX_LO(acc, pk, w) asm("v_fma_mix_f32 %0, %1, %2, %0 op_sel:[0,0,0] op_sel_hi:[1,0,0]" : "+v"(acc) : "v"(pk), "v"(w))
#define MIX_HI(acc, pk, w) asm("v_fma_mix_f32 %0, %1, %2, %0 op_sel:[1,0,0] op_sel_hi:[1,0,0]" : "+v"(acc) : "v"(pk), "v"(w))

// ---------------- tf0 MFMA body: 8 waves/block(512), 16 rows/wave -------------
__device__ __forceinline__ void gemm_body(
    int gb, const float* __restrict__ x, int N,
    __half* __restrict__ xw, float* __restrict__ as, float* __restrict__ ad,
    h8_t* Bl)
{
    int wave = threadIdx.x >> 6, lane = threadIdx.x & 63;
    int row0 = gb * 128 + wave * 16;
    if (row0 >= N) return;
    int quad = lane >> 4, c16 = lane & 15;
    int myrow = min(row0 + c16, N - 1);
    const float* xr = x + (size_t)myrow * 128;
    h8_t a[4];
    #pragma unroll
    for (int ks = 0; ks < 4; ks++) {
        int kb = ks * 32 + quad * 8;
        float4 v0 = *(const float4*)(xr + kb);
        float4 v1 = *(const float4*)(xr + kb + 4);
        h8_t av;
        av[0] = (_Float16)v0.x; av[1] = (_Float16)v0.y;
        av[2] = (_Float16)v0.z; av[3] = (_Float16)v0.w;
        av[4] = (_Float16)v1.x; av[5] = (_Float16)v1.y;
        av[6] = (_Float16)v1.z; av[7] = (_Float16)v1.w;
        a[ks] = av;
    }
    int rbase = row0 + quad * 4;
    #pragma unroll
    for (int ct = 0; ct < 5; ct++) {
        f4_t acc = {0.f, 0.f, 0.f, 0.f};
        #pragma unroll
        for (int ks = 0; ks < 4; ks++) {
            h8_t b = Bl[(ct * 4 + ks) * 64 + lane];
            acc = __builtin_amdgcn_mfma_f32_16x16x32_f16(a[ks], b, acc, 0, 0, 0);
        }
        if (ct < 4) {
            int col = ct * 16 + c16;
            #pragma unroll
            for (int r = 0; r < 4; r++) {
                int row = rbase + r;
                if (row < N) xw[(size_t)row * 64 + col] = __float2half(acc[r]);
            }
        } else {
            #pragma unroll
            for (int r = 0; r < 4; r++) {
                int row = rbase + r;
                if (row < N) {
                    float sc = acc[r] * LOG2E;   // pre-scale logits: exp -> exp2
                    if (c16 < 8) as[(size_t)row * 8 + c16] = sc;
                    else         ad[(size_t)row * 8 + (c16 - 8)] = sc;
                }
            }
        }
    }
}

// ---------------- fused: gemm0 || single-pass binning ----------------
// gemm blocks build the swizzled W0 image [ct][ks][quad][col][j] in LDS
// directly from W0/att (kPrep eliminated — it was a 1-block serial bubble).
__global__ __launch_bounds__(512, 4) void kGB(
    const float* __restrict__ x, const float* __restrict__ W0,
    const float* __restrict__ aS0, const float* __restrict__ aD0, int N,
    __half* __restrict__ xw, float* __restrict__ as, float* __restrict__ ad,
    int gemmBlocks,
    const int* __restrict__ src, const int* __restrict__ dst, int E, int perBlock,
    unsigned* __restrict__ bucketBuf, int* __restrict__ gcur, int NB, int cap,
    int binBlocks)
{
    __shared__ __align__(16) char smem[NBMAX * STRIDE * 4 + NBMAX * 4]; // 36.9 KB union
    int b = blockIdx.x;
    int T = gemmBlocks + binBlocks;
    int lo = (int)((long long)b * gemmBlocks / T);
    int hi = (int)((long long)(b + 1) * gemmBlocks / T);
    if (hi > lo) {
        h8_t* Bl = (h8_t*)smem;
        for (int g = threadIdx.x; g < 1280; g += 512) {
            int col  = g & 15;
            int quad = (g >> 4) & 3;
            int ks   = (g >> 6) & 3;
            int ct   = g >> 8;
            h8_t av;
            if (ct < 4) {
                #pragma unroll
                for (int j = 0; j < 8; j++) {
                    int k = ks * 32 + quad * 8 + j;
                    av[j] = (_Float16)W0[k * 64 + ct * 16 + col];
                }
            } else {
                int h = col & 7;
                const float* att = (col < 8) ? aS0 : aD0;
                #pragma unroll
                for (int j = 0; j < 8; j++) {
                    int k = ks * 32 + quad * 8 + j;
                    float v = 0.f;
                    #pragma unroll
                    for (int cc = 0; cc < 8; cc++)
                        v += W0[k * 64 + h * 8 + cc] * att[h * 8 + cc];
                    av[j] = (_Float16)v;
                }
            }
            Bl[g] = av;
        }
        __syncthreads();
        gemm_body(lo, x, N, xw, as, ad, Bl);
    } else {
        int pb = b - hi;
        unsigned* stage = (unsigned*)smem;
        int* scnt = (int*)(smem + NBMAX * STRIDE * 4);
        int tid = threadIdx.x;
        for (int i = tid; i < NB; i += 512) scnt[i] = 0;
        __syncthreads();
        int e0 = pb * perBlock, e1 = min(E, e0 + perBlock);
        for (int i = e0 + tid; i < e1; i += 512) {
            int d2 = dst[i], s2 = src[i];
            int bk = d2 >> 8;                              // 256-node buckets
            unsigned rec = ((unsigned)(d2 & 255) << 22) | (unsigned)s2;
            int pos = atomicAdd(&scnt[bk], 1);
            if (pos < CAPS) {
                stage[bk * STRIDE + pos] = rec;
            } else {
                int g = atomicAdd(&gcur[bk], 1);
                if (g < cap) bucketBuf[(size_t)bk * cap + g] = rec;
            }
        }
        __syncthreads();
        for (int t = tid; t < NB; t += 512) {
            int n = min(scnt[t], CAPS);
            if (n > 0) {
                int gb2 = atomicAdd(&gcur[t], n);
                unsigned* gp = &bucketBuf[(size_t)t * cap + gb2];
                for (int j = 0; j < n; j++)
                    if (gb2 + j < cap) gp[j] = stage[t * STRIDE + j];
            }
        }
    }
}

// ---------------- phase2: per-bucket CSR build (256-node buckets) ----------
__global__ __launch_bounds__(256) void kP2(
    const unsigned* __restrict__ bucketBuf, const int* __restrict__ gcur,
    int NB, int cap, int N, int* __restrict__ row, int* __restrict__ adj)
{
    __shared__ int deg[256];
    __shared__ int curl[256];
    __shared__ int sc[256];
    int b = blockIdx.x, tid = threadIdx.x;
    int lo = b << 8;
    int hi = min(N, lo + 256);
    int cnt = hi - lo;
    int size = min(gcur[b], cap);
    int part = 0;
    for (int i = tid; i < b; i += 256) part += min(gcur[i], cap);
    sc[tid] = part;
    __syncthreads();
    for (int off = 128; off > 0; off >>= 1) {
        if (tid < off) sc[tid] += sc[tid + off];
        __syncthreads();
    }
    int bbase = sc[0];
    __syncthreads();
    deg[tid] = 0;
    __syncthreads();
    const unsigned* buf = bucketBuf + (size_t)b * cap;
    for (int e = tid; e < size; e += 256) atomicAdd(&deg[buf[e] >> 22], 1);
    __syncthreads();
    int d = deg[tid];
    sc[tid] = d;
    __syncthreads();
    for (int off = 1; off < 256; off <<= 1) {
        int xv = (tid >= off) ? sc[tid - off] : 0;
        __syncthreads();
        sc[tid] += xv;
        __syncthreads();
    }
    int o = (tid ? sc[tid - 1] : 0);
    curl[tid] = o;
    if (tid < cnt) row[lo + tid] = bbase + o;
    if (b == NB - 1 && tid == 0) row[N] = bbase + size;
    __syncthreads();
    for (int e = tid; e < size; e += 256) {
        unsigned r = buf[e];
        int l = r >> 22;
        int p = atomicAdd(&curl[l], 1);
        adj[bbase + p] = (int)(r & 0x3FFFFF);
    }
}

// ---------------- layer0 aggregation: 2 nodes/wave, depth-2 pipeline --------
// wave = 2 halves of 32 lanes; each half owns one node. Within a half:
// e4 = sub>>3 (4 edge slots), hh = sub&7 (head == 16B chunk).
// 2-phase manual unroll: adj prefetched 2 iters ahead, gathers 1 ahead.
// Masked adj reads fall back to index 0 (always valid).
__global__ __launch_bounds__(256) void k_agg8(
    const __half* __restrict__ xw, const float* __restrict__ as, const float* __restrict__ ad,
    const int* __restrict__ row, const int* __restrict__ adj,
    const float* __restrict__ bias, int N, __half* __restrict__ hbuf)
{
    int n = (blockIdx.x * 256 + threadIdx.x) >> 5;   // 8 nodes per block
    int lane = threadIdx.x & 63;
    int sub  = lane & 31;
    if (n >= N) return;
    int e4 = sub >> 3;
    int hh = sub & 7;
    int rs = row[n], re = row[n + 1];
    const u4_t* xwv = (const u4_t*)xw;               // row stride = 8 chunks
    float adv = ad[(unsigned)n * 8u + hh];
    float shift = lrelu(as[(unsigned)n * 8u + hh] + adv);
    float accv[8];
    #pragma unroll
    for (int k = 0; k < 8; k++) accv[k] = 0.f;
    float dsum = 0.f;

    int j = rs;
    bool vA0 = j + e4 < re,      vB0 = j + 4 + e4 < re;
    int  sA0 = adj[(unsigned)(vA0 ? j + e4 : 0)];
    int  sB0 = adj[(unsigned)(vB0 ? j + 4 + e4 : 0)];
    bool vA1 = j + 8 + e4 < re,  vB1 = j + 12 + e4 < re;
    int  sA1 = adj[(unsigned)(vA1 ? j + 8 + e4 : 0)];
    int  sB1 = adj[(unsigned)(vB1 ? j + 12 + e4 : 0)];
    float eA0 = lrelu(as[(unsigned)sA0 * 8u + hh] + adv);
    float eB0 = lrelu(as[(unsigned)sB0 * 8u + hh] + adv);
    u4_t xA0 = xwv[(unsigned)sA0 * 8u + hh];
    u4_t xB0 = xwv[(unsigned)sB0 * 8u + hh];
    float eA1, eB1; u4_t xA1, xB1;

    for (;;) {
        // phase even: prefetch adj(j+16)->slot0, gathers slot1, compute slot0
        {
            bool vA2 = j + 16 + e4 < re, vB2 = j + 20 + e4 < re;
            int nsA = adj[(unsigned)(vA2 ? j + 16 + e4 : 0)];
            int nsB = adj[(unsigned)(vB2 ? j + 20 + e4 : 0)];
            eA1 = lrelu(as[(unsigned)sA1 * 8u + hh] + adv);
            eB1 = lrelu(as[(unsigned)sB1 * 8u + hh] + adv);
            xA1 = xwv[(unsigned)sA1 * 8u + hh];
            xB1 = xwv[(unsigned)sB1 * 8u + hh];
            float wA = vA0 ? __builtin_amdgcn_exp2f(eA0 - shift) : 0.f;
            float wB = vB0 ? __builtin_amdgcn_exp2f(eB0 - shift) : 0.f;
            dsum += wA + wB;
            #pragma unroll
            for (int q = 0; q < 4; q++) {
                MIX_LO(accv[2 * q],     xA0[q], wA);
                MIX_HI(accv[2 * q + 1], xA0[q], wA);
            }
            #pragma unroll
            for (int q = 0; q < 4; q++) {
                MIX_LO(accv[2 * q],     xB0[q], wB);
                MIX_HI(accv[2 * q + 1], xB0[q], wB);
            }
            vA0 = vA2; vB0 = vB2; sA0 = nsA; sB0 = nsB;
        }
        j += 8;
        if (!__any(vA1)) break;
        // phase odd: prefetch adj(j+16)->slot1, gathers slot0, compute slot1
        {
            bool vA2 = j + 16 + e4 < re, vB2 = j + 20 + e4 < re;
            int nsA = adj[(unsigned)(vA2 ? j + 16 + e4 : 0)];
            int nsB = adj[(unsigned)(vB2 ? j + 20 + e4 : 0)];
            eA0 = lrelu(as[(unsigned)sA0 * 8u + hh] + adv);
            eB0 = lrelu(as[(unsigned)sB0 * 8u + hh] + adv);
            xA0 = xwv[(unsigned)sA0 * 8u + hh];
            xB0 = xwv[(unsigned)sB0 * 8u + hh];
            float wA = vA1 ? __builtin_amdgcn_exp2f(eA1 - shift) : 0.f;
            float wB = vB1 ? __builtin_amdgcn_exp2f(eB1 - shift) : 0.f;
            dsum += wA + wB;
            #pragma unroll
            for (int q = 0; q < 4; q++) {
                MIX_LO(accv[2 * q],     xA1[q], wA);
                MIX_HI(accv[2 * q + 1], xA1[q], wA);
            }
            #pragma unroll
            for (int q = 0; q < 4; q++) {
                MIX_LO(accv[2 * q],     xB1[q], wB);
                MIX_HI(accv[2 * q + 1], xB1[q], wB);
            }
            vA1 = vA2; vB1 = vB2; sA1 = nsA; sB1 = nsB;
        }
        j += 8;
        if (!__any(vA0)) break;
    }
    #pragma unroll
    for (int k = 0; k < 8; k++) {
        accv[k] += __shfl_xor(accv[k], 8, 64);
        accv[k] += __shfl_xor(accv[k], 16, 64);
    }
    dsum += __shfl_xor(dsum, 8, 64);
    dsum += __shfl_xor(dsum, 16, 64);
    if (e4 == 0) {
        float inv = 1.f / (1.f + dsum);              // self-loop weight = 1
        h8_t sv = *(const h8_t*)(xw + (size_t)n * 64 + hh * 8);
        float4 b0 = *(const float4*)(bias + hh * 8);
        float4 b1 = *(const float4*)(bias + hh * 8 + 4);
        float bb[8] = {b0.x, b0.y, b0.z, b0.w, b1.x, b1.y, b1.z, b1.w};
        h8_t o;
        #pragma unroll
        for (int k = 0; k < 8; k++) {
            float v = (accv[k] + (float)sv[k]) * inv + bb[k];
            o[k] = (_Float16)eluf(v);
        }
        *(h8_t*)(hbuf + (size_t)n * 64 + hh * 8) = o;
    }
}

// ---------------- layer1 transform: h @ W1 via MFMA (K=64) + as1/ad1 --------
// builds its swizzled W1 image [ct][ks][quad][col][j] in LDS from W1 directly.
__global__ __launch_bounds__(512, 4) void kTF1(
    const __half* __restrict__ h, const float* __restrict__ W1,
    const float* __restrict__ aS1, const float* __restrict__ aD1, int N,
    __half* __restrict__ hw, float* __restrict__ as1, float* __restrict__ ad1)
{
    __shared__ __align__(16) h8_t Bl[512];
    {
        int g = threadIdx.x;                 // 512 threads, one group each
        int col  = g & 15;
        int quad = (g >> 4) & 3;
        int ks   = (g >> 6) & 1;
        int ct   = g >> 7;
        h8_t av;
        #pragma unroll
        for (int j = 0; j < 8; j++) {
            int k = ks * 32 + quad * 8 + j;
            av[j] = (_Float16)W1[k * 64 + ct * 16 + col];
        }
        Bl[g] = av;
    }
    __syncthreads();
    int wave = threadIdx.x >> 6, lane = threadIdx.x & 63;
    int row0 = blockIdx.x * 128 + wave * 16;
    if (row0 >= N) return;
    int quad = lane >> 4, c16 = lane & 15;
    int myrow = min(row0 + c16, N - 1);
    const __half* hr = h + (size_t)myrow * 64;
    h8_t a0 = *(const h8_t*)(hr + quad * 8);
    h8_t a1 = *(const h8_t*)(hr + 32 + quad * 8);
    int rbase = row0 + quad * 4;
    float ps[4] = {0.f, 0.f, 0.f, 0.f};
    float pd[4] = {0.f, 0.f, 0.f, 0.f};
    #pragma unroll
    for (int ct = 0; ct < 4; ct++) {
        f4_t acc = {0.f, 0.f, 0.f, 0.f};
        acc = __builtin_amdgcn_mfma_f32_16x16x32_f16(a0, Bl[(ct * 2 + 0) * 64 + lane], acc, 0, 0, 0);
        acc = __builtin_amdgcn_mfma_f32_16x16x32_f16(a1, Bl[(ct * 2 + 1) * 64 + lane], acc, 0, 0, 0);
        float s1c = aS1[ct * 16 + c16];
        float d1c = aD1[ct * 16 + c16];
        int col = ct * 16 + c16;
        #pragma unroll
        for (int r = 0; r < 4; r++) {
            int rr = rbase + r;
            if (rr < N) hw[(size_t)rr * 64 + col] = __float2half(acc[r]);
            ps[r] = fmaf(acc[r], s1c, ps[r]);
            pd[r] = fmaf(acc[r], d1c, pd[r]);
        }
    }
    #pragma unroll
    for (int r = 0; r < 4; r++) {
        #pragma unroll
        for (int off = 1; off < 16; off <<= 1) {
            ps[r] += __shfl_xor(ps[r], off, 64);
            pd[r] += __shfl_xor(pd[r], off, 64);
        }
    }
    if (c16 == 0) {
        #pragma unroll
        for (int r = 0; r < 4; r++) {
            int rr = rbase + r;
            if (rr < N) { as1[rr] = ps[r] * LOG2E; ad1[rr] = pd[r] * LOG2E; }
        }
    }
}

// ---------------- layer1 aggregation: 2 nodes/wave, depth-2 pipeline --------
__global__ __launch_bounds__(256) void k_agg1(
    const __half* __restrict__ hw, const float* __restrict__ as, const float* __restrict__ ad,
    const int* __restrict__ row, const int* __restrict__ adj,
    const float* __restrict__ bias, int N, float* __restrict__ outp)
{
    int n = (blockIdx.x * 256 + threadIdx.x) >> 5;   // 8 nodes per block
    int lane = threadIdx.x & 63;
    int sub  = lane & 31;
    if (n >= N) return;
    int e4 = sub >> 3;
    int hh = sub & 7;
    int rs = row[n], re = row[n + 1];
    const u4_t* hwv = (const u4_t*)hw;
    float adv = ad[n];
    float shift = lrelu(as[n] + adv);
    float accv[8];
    #pragma unroll
    for (int k = 0; k < 8; k++) accv[k] = 0.f;
    float dsum = 0.f;

    int j = rs;
    bool vA0 = j + e4 < re,      vB0 = j + 4 + e4 < re;
    int  sA0 = adj[(unsigned)(vA0 ? j + e4 : 0)];
    int  sB0 = adj[(unsigned)(vB0 ? j + 4 + e4 : 0)];
    bool vA1 = j + 8 + e4 < re,  vB1 = j + 12 + e4 < re;
    int  sA1 = adj[(unsigned)(vA1 ? j + 8 + e4 : 0)];
    int  sB1 = adj[(unsigned)(vB1 ? j + 12 + e4 : 0)];
    float eA0 = lrelu(as[(unsigned)sA0] + adv);
    float eB0 = lrelu(as[(unsigned)sB0] + adv);
    u4_t xA0 = hwv[(unsigned)sA0 * 8u + hh];
    u4_t xB0 = hwv[(unsigned)sB0 * 8u + hh];
    float eA1, eB1; u4_t xA1, xB1;

    for (;;) {
        // phase even
        {
            bool vA2 = j + 16 + e4 < re, vB2 = j + 20 + e4 < re;
            int nsA = adj[(unsigned)(vA2 ? j + 16 + e4 : 0)];
            int nsB = adj[(unsigned)(vB2 ? j + 20 + e4 : 0)];
            eA1 = lrelu(as[(unsigned)sA1] + adv);
            eB1 = lrelu(as[(unsigned)sB1] + adv);
            xA1 = hwv[(unsigned)sA1 * 8u + hh];
            xB1 = hwv[(unsigned)sB1 * 8u + hh];
            float wA = vA0 ? __builtin_amdgcn_exp2f(eA0 - shift) : 0.f;
            float wB = vB0 ? __builtin_amdgcn_exp2f(eB0 - shift) : 0.f;
            dsum += wA + wB;
            #pragma unroll
            for (int q = 0; q < 4; q++) {
                MIX_LO(accv[2 * q],     xA0[q], wA);
                MIX_HI(accv[2 * q + 1], xA0[q], wA);
            }
            #pragma unroll
            for (int q = 0; q < 4; q++) {
                MIX_LO(accv[2 * q],     xB0[q], wB);
                MIX_HI(accv[2 * q + 1], xB0[q], wB);
            }
            vA0 = vA2; vB0 = vB2; sA0 = nsA; sB0 = nsB;
        }
        j += 8;
        if (!__any(vA1)) break;
        // phase odd
        {
            bool vA2 = j + 16 + e4 < re, vB2 = j + 20 + e4 < re;
            int nsA = adj[(unsigned)(vA2 ? j + 16 + e4 : 0)];
            int nsB = adj[(unsigned)(vB2 ? j + 20 + e4 : 0)];
            eA0 = lrelu(as[(unsigned)sA0] + adv);
            eB0 = lrelu(as[(unsigned)sB0] + adv);
            xA0 = hwv[(unsigned)sA0 * 8u + hh];
            xB0 = hwv[(unsigned)sB0 * 8u + hh];
            float wA = vA1 ? __builtin_amdgcn_exp2f(eA1 - shift) : 0.f;
            float wB = vB1 ? __builtin_amdgcn_exp2f(eB1 - shift) : 0.f;
            dsum += wA + wB;
            #pragma unroll
            for (int q = 0; q < 4; q++) {
                MIX_LO(accv[2 * q],     xA1[q], wA);
                MIX_HI(accv[2 * q + 1], xA1[q], wA);
            }
            #pragma unroll
            for (int q = 0; q < 4; q++) {
                MIX_LO(accv[2 * q],     xB1[q], wB);
                MIX_HI(accv[2 * q + 1], xB1[q], wB);
            }
            vA1 = vA2; vB1 = vB2; sA1 = nsA; sB1 = nsB;
        }
        j += 8;
        if (!__any(vA0)) break;
    }
    #pragma unroll
    for (int k = 0; k < 8; k++) {
        accv[k] += __shfl_xor(accv[k], 8, 64);
        accv[k] += __shfl_xor(accv[k], 16, 64);
    }
    dsum += __shfl_xor(dsum, 8, 64);
    dsum += __shfl_xor(dsum, 16, 64);
    if (e4 == 0) {
        float inv = 1.f / (1.f + dsum);
        h8_t sv = *(const h8_t*)(hw + (size_t)n * 64 + hh * 8);
        float4 b0 = *(const float4*)(bias + hh * 8);
        float4 b1 = *(const float4*)(bias + hh * 8 + 4);
        float bb[8] = {b0.x, b0.y, b0.z, b0.w, b1.x, b1.y, b1.z, b1.w};
        float ov[8];
        #pragma unroll
        for (int k = 0; k < 8; k++)
            ov[k] = eluf((accv[k] + (float)sv[k]) * inv + bb[k]);
        float4 o0 = {ov[0], ov[1], ov[2], ov[3]};
        float4 o1 = {ov[4], ov[5], ov[6], ov[7]};
        float4* op = (float4*)(outp + (size_t)n * 64 + hh * 8);
        op[0] = o0;
        op[1] = o1;
    }
}

extern "C" void kernel_launch(void* const* d_in, const int* in_sizes, int n_in,
                              void* d_out, int out_size, void* d_ws, size_t ws_size,
                              hipStream_t stream)
{
    const float* x   = (const float*)d_in[0];
    const int*   ei  = (const int*)d_in[1];
    const float* W0  = (const float*)d_in[2];
    const float* aS0 = (const float*)d_in[3];
    const float* aD0 = (const float*)d_in[4];
    const float* b0  = (const float*)d_in[5];
    const float* W1  = (const float*)d_in[6];
    const float* aS1 = (const float*)d_in[7];
    const float* aD1 = (const float*)d_in[8];
    const float* b1  = (const float*)d_in[9];

    const int N = in_sizes[0] / 128;
    const int E = in_sizes[1] / 2;
    const int* srcp = ei;
    const int* dstp = ei + E;

    const int NB  = (N + 255) >> 8;          // 256-node buckets
    const int cap = E / NB + 4096;

    char* ws = (char*)d_ws;
    size_t off = 0;
    auto alloc = [&](size_t bytes) -> size_t {
        size_t o = off;
        off = (o + bytes + 255) & ~(size_t)255;
        return o;
    };
    __half* B1 = (__half*)(ws + alloc((size_t)N * 64 * 2));     // xw (half); later reused as hw
    size_t b2Bytes = (size_t)N * 64 * 2;
    size_t bkBytes = (size_t)NB * cap * 4;
    char*  region  = ws + alloc(b2Bytes > bkBytes ? b2Bytes : bkBytes);
    __half*   B2        = (__half*)region;     // h overlays bucketBuf (dead after kP2)
    unsigned* bucketBuf = (unsigned*)region;
    float* as0 = (float*)(ws + alloc((size_t)N * 8 * 4));
    float* ad0 = (float*)(ws + alloc((size_t)N * 8 * 4));
    float* as1 = (float*)(ws + alloc((size_t)N * 4));
    float* ad1 = (float*)(ws + alloc((size_t)N * 4));
    int*   row = (int*)(ws + alloc((size_t)(N + 1) * 4));
    int*   adj = (int*)(ws + alloc((size_t)E * 4));
    int*  gcur = (int*)(ws + alloc((size_t)NB * 4));

    const int gemmBlocks = (N + 127) / 128;
    const int binBlocks  = 512;
    const int perBlock   = (E + binBlocks - 1) / binBlocks;

    hipMemsetAsync(gcur, 0, (size_t)NB * 4, stream);
    kGB<<<gemmBlocks + binBlocks, 512, 0, stream>>>(
        x, W0, aS0, aD0, N, B1, as0, ad0, gemmBlocks,
        srcp, dstp, E, perBlock, bucketBuf, gcur, NB, cap, binBlocks);
    kP2<<<NB, 256, 0, stream>>>(bucketBuf, gcur, NB, cap, N, row, adj);

    const int agBlocks = (N + 7) / 8;   // 8 nodes per 256-thread block
    // layer-0 aggregation: reads xw (B1), writes h (B2, over dead bucketBuf)
    k_agg8<<<agBlocks, 256, 0, stream>>>(B1, as0, ad0, row, adj, b0, N, B2);
    // layer-1 transform: reads h (B2), writes hw into B1 (xw dead) + as1/ad1
    kTF1<<<(N + 127) / 128, 512, 0, stream>>>(B2, W1, aS1, aD1, N, B1, as1, ad1);
    // layer-1 aggregation
    k_agg1<<<agBlocks, 256, 0, stream>>>(B1, as1, ad1, row, adj, b1, N, (float*)d_out);
}

// Round 8
// 244.637 us; speedup vs baseline: 1.3843x; 1.0024x over previous
//
#include <hip/hip_runtime.h>
#include <hip/hip_fp16.h>
#include <math.h>

// GAT 2-layer. R21: agg kernels — 4 nodes/wave (16 lanes/node: 2 edge slots
// x 8 head-chunks), depth-2 pipeline with halved offsets. Same instruction
// count and registers per phase as the 2-node version (16 edges/wave/phase),
// but tail+prologue gather waste halves (avg degree ~17 vs 8-edge groups was
// ~15% junk slots) and the cross-edge reduce is a single xor-8. 512-thread
// agg blocks. kGB/kP2/kTF1 unchanged from R20.

#define CAPS 16
#define STRIDE 17
#define NBMAX 512
#define LOG2E 1.44269504f

typedef _Float16 h2_t  __attribute__((ext_vector_type(2)));
typedef _Float16 h8_t  __attribute__((ext_vector_type(8)));
typedef float    f4_t  __attribute__((ext_vector_type(4)));
typedef unsigned int u4_t __attribute__((ext_vector_type(4)));

__device__ __forceinline__ float lrelu(float v) { return v >= 0.f ? v : 0.2f * v; }
__device__ __forceinline__ float eluf(float v)  {
    return v > 0.f ? v : __builtin_amdgcn_exp2f(v * LOG2E) - 1.f;
}

// acc += (float)lo_half(pk) * w   /   acc += (float)hi_half(pk) * w
#define MIX_LO(acc, pk, w) asm("v_fma_mix_f32 %0, %1, %2, %0 op_sel:[0,0,0] op_sel_hi:[1,0,0]" : "+v"(acc) : "v"(pk), "v"(w))
#define MIX_HI(acc, pk, w) asm("v_fma_mix_f32 %0, %1, %2, %0 op_sel:[1,0,0] op_sel_hi:[1,0,0]" : "+v"(acc) : "v"(pk), "v"(w))

// ---------------- tf0 MFMA body: 8 waves/block(512), 16 rows/wave -------------
__device__ __forceinline__ void gemm_body(
    int gb, const float* __restrict__ x, int N,
    __half* __restrict__ xw, float* __restrict__ as, float* __restrict__ ad,
    h8_t* Bl)
{
    int wave = threadIdx.x >> 6, lane = threadIdx.x & 63;
    int row0 = gb * 128 + wave * 16;
    if (row0 >= N) return;
    int quad = lane >> 4, c16 = lane & 15;
    int myrow = min(row0 + c16, N - 1);
    const float* xr = x + (size_t)myrow * 128;
    h8_t a[4];
    #pragma unroll
    for (int ks = 0; ks < 4; ks++) {
        int kb = ks * 32 + quad * 8;
        float4 v0 = *(const float4*)(xr + kb);
        float4 v1 = *(const float4*)(xr + kb + 4);
        h8_t av;
        av[0] = (_Float16)v0.x; av[1] = (_Float16)v0.y;
        av[2] = (_Float16)v0.z; av[3] = (_Float16)v0.w;
        av[4] = (_Float16)v1.x; av[5] = (_Float16)v1.y;
        av[6] = (_Float16)v1.z; av[7] = (_Float16)v1.w;
        a[ks] = av;
    }
    int rbase = row0 + quad * 4;
    #pragma unroll
    for (int ct = 0; ct < 5; ct++) {
        f4_t acc = {0.f, 0.f, 0.f, 0.f};
        #pragma unroll
        for (int ks = 0; ks < 4; ks++) {
            h8_t b = Bl[(ct * 4 + ks) * 64 + lane];
            acc = __builtin_amdgcn_mfma_f32_16x16x32_f16(a[ks], b, acc, 0, 0, 0);
        }
        if (ct < 4) {
            int col = ct * 16 + c16;
            #pragma unroll
            for (int r = 0; r < 4; r++) {
                int row = rbase + r;
                if (row < N) xw[(size_t)row * 64 + col] = __float2half(acc[r]);
            }
        } else {
            #pragma unroll
            for (int r = 0; r < 4; r++) {
                int row = rbase + r;
                if (row < N) {
                    float sc = acc[r] * LOG2E;   // pre-scale logits: exp -> exp2
                    if (c16 < 8) as[(size_t)row * 8 + c16] = sc;
                    else         ad[(size_t)row * 8 + (c16 - 8)] = sc;
                }
            }
        }
    }
}

// ---------------- fused: gemm0 || single-pass binning ----------------
__global__ __launch_bounds__(512, 4) void kGB(
    const float* __restrict__ x, const float* __restrict__ W0,
    const float* __restrict__ aS0, const float* __restrict__ aD0, int N,
    __half* __restrict__ xw, float* __restrict__ as, float* __restrict__ ad,
    int gemmBlocks,
    const int* __restrict__ src, const int* __restrict__ dst, int E, int perBlock,
    unsigned* __restrict__ bucketBuf, int* __restrict__ gcur, int NB, int cap,
    int binBlocks)
{
    __shared__ __align__(16) char smem[NBMAX * STRIDE * 4 + NBMAX * 4]; // 36.9 KB union
    int b = blockIdx.x;
    int T = gemmBlocks + binBlocks;
    int lo = (int)((long long)b * gemmBlocks / T);
    int hi = (int)((long long)(b + 1) * gemmBlocks / T);
    if (hi > lo) {
        h8_t* Bl = (h8_t*)smem;
        for (int g = threadIdx.x; g < 1280; g += 512) {
            int col  = g & 15;
            int quad = (g >> 4) & 3;
            int ks   = (g >> 6) & 3;
            int ct   = g >> 8;
            h8_t av;
            if (ct < 4) {
                #pragma unroll
                for (int j = 0; j < 8; j++) {
                    int k = ks * 32 + quad * 8 + j;
                    av[j] = (_Float16)W0[k * 64 + ct * 16 + col];
                }
            } else {
                int h = col & 7;
                const float* att = (col < 8) ? aS0 : aD0;
                #pragma unroll
                for (int j = 0; j < 8; j++) {
                    int k = ks * 32 + quad * 8 + j;
                    float v = 0.f;
                    #pragma unroll
                    for (int cc = 0; cc < 8; cc++)
                        v += W0[k * 64 + h * 8 + cc] * att[h * 8 + cc];
                    av[j] = (_Float16)v;
                }
            }
            Bl[g] = av;
        }
        __syncthreads();
        gemm_body(lo, x, N, xw, as, ad, Bl);
    } else {
        int pb = b - hi;
        unsigned* stage = (unsigned*)smem;
        int* scnt = (int*)(smem + NBMAX * STRIDE * 4);
        int tid = threadIdx.x;
        for (int i = tid; i < NB; i += 512) scnt[i] = 0;
        __syncthreads();
        int e0 = pb * perBlock, e1 = min(E, e0 + perBlock);
        for (int i = e0 + tid; i < e1; i += 512) {
            int d2 = dst[i], s2 = src[i];
            int bk = d2 >> 8;                              // 256-node buckets
            unsigned rec = ((unsigned)(d2 & 255) << 22) | (unsigned)s2;
            int pos = atomicAdd(&scnt[bk], 1);
            if (pos < CAPS) {
                stage[bk * STRIDE + pos] = rec;
            } else {
                int g = atomicAdd(&gcur[bk], 1);
                if (g < cap) bucketBuf[(size_t)bk * cap + g] = rec;
            }
        }
        __syncthreads();
        for (int t = tid; t < NB; t += 512) {
            int n = min(scnt[t], CAPS);
            if (n > 0) {
                int gb2 = atomicAdd(&gcur[t], n);
                unsigned* gp = &bucketBuf[(size_t)t * cap + gb2];
                for (int j = 0; j < n; j++)
                    if (gb2 + j < cap) gp[j] = stage[t * STRIDE + j];
            }
        }
    }
}

// ---------------- phase2: per-bucket CSR build (256-node buckets) ----------
__global__ __launch_bounds__(256) void kP2(
    const unsigned* __restrict__ bucketBuf, const int* __restrict__ gcur,
    int NB, int cap, int N, int* __restrict__ row, int* __restrict__ adj)
{
    __shared__ int deg[256];
    __shared__ int curl[256];
    __shared__ int sc[256];
    int b = blockIdx.x, tid = threadIdx.x;
    int lo = b << 8;
    int hi = min(N, lo + 256);
    int cnt = hi - lo;
    int size = min(gcur[b], cap);
    int part = 0;
    for (int i = tid; i < b; i += 256) part += min(gcur[i], cap);
    sc[tid] = part;
    __syncthreads();
    for (int off = 128; off > 0; off >>= 1) {
        if (tid < off) sc[tid] += sc[tid + off];
        __syncthreads();
    }
    int bbase = sc[0];
    __syncthreads();
    deg[tid] = 0;
    __syncthreads();
    const unsigned* buf = bucketBuf + (size_t)b * cap;
    for (int e = tid; e < size; e += 256) atomicAdd(&deg[buf[e] >> 22], 1);
    __syncthreads();
    int d = deg[tid];
    sc[tid] = d;
    __syncthreads();
    for (int off = 1; off < 256; off <<= 1) {
        int xv = (tid >= off) ? sc[tid - off] : 0;
        __syncthreads();
        sc[tid] += xv;
        __syncthreads();
    }
    int o = (tid ? sc[tid - 1] : 0);
    curl[tid] = o;
    if (tid < cnt) row[lo + tid] = bbase + o;
    if (b == NB - 1 && tid == 0) row[N] = bbase + size;
    __syncthreads();
    for (int e = tid; e < size; e += 256) {
        unsigned r = buf[e];
        int l = r >> 22;
        int p = atomicAdd(&curl[l], 1);
        adj[bbase + p] = (int)(r & 0x3FFFFF);
    }
}

// ---------------- layer0 aggregation: 4 nodes/wave, depth-2 pipeline --------
// 16 lanes/node: e2 = (lane&15)>>3 (2 edge slots), hh = lane&7 (head=chunk).
// Per phase: 4 edges/node (A: j+e2, B: j+2+e2), adj prefetched 2 groups
// ahead, gathers 1 ahead. Masked adj reads fall back to index 0.
__global__ __launch_bounds__(512) void k_agg8(
    const __half* __restrict__ xw, const float* __restrict__ as, const float* __restrict__ ad,
    const int* __restrict__ row, const int* __restrict__ adj,
    const float* __restrict__ bias, int N, __half* __restrict__ hbuf)
{
    int n = (blockIdx.x * 512 + threadIdx.x) >> 4;   // 32 nodes per block
    int sub  = threadIdx.x & 15;
    if (n >= N) return;
    int e2 = sub >> 3;
    int hh = sub & 7;
    int rs = row[n], re = row[n + 1];
    const u4_t* xwv = (const u4_t*)xw;               // row stride = 8 chunks
    float adv = ad[(unsigned)n * 8u + hh];
    float shift = lrelu(as[(unsigned)n * 8u + hh] + adv);
    float accv[8];
    #pragma unroll
    for (int k = 0; k < 8; k++) accv[k] = 0.f;
    float dsum = 0.f;

    int j = rs;
    bool vA0 = j + e2 < re,     vB0 = j + 2 + e2 < re;
    int  sA0 = adj[(unsigned)(vA0 ? j + e2 : 0)];
    int  sB0 = adj[(unsigned)(vB0 ? j + 2 + e2 : 0)];
    bool vA1 = j + 4 + e2 < re, vB1 = j + 6 + e2 < re;
    int  sA1 = adj[(unsigned)(vA1 ? j + 4 + e2 : 0)];
    int  sB1 = adj[(unsigned)(vB1 ? j + 6 + e2 : 0)];
    float eA0 = lrelu(as[(unsigned)sA0 * 8u + hh] + adv);
    float eB0 = lrelu(as[(unsigned)sB0 * 8u + hh] + adv);
    u4_t xA0 = xwv[(unsigned)sA0 * 8u + hh];
    u4_t xB0 = xwv[(unsigned)sB0 * 8u + hh];
    float eA1, eB1; u4_t xA1, xB1;

    for (;;) {
        // phase even: prefetch adj(j+8)->slot0, gathers slot1, compute slot0
        {
            bool vA2 = j + 8 + e2 < re, vB2 = j + 10 + e2 < re;
            int nsA = adj[(unsigned)(vA2 ? j + 8 + e2 : 0)];
            int nsB = adj[(unsigned)(vB2 ? j + 10 + e2 : 0)];
            eA1 = lrelu(as[(unsigned)sA1 * 8u + hh] + adv);
            eB1 = lrelu(as[(unsigned)sB1 * 8u + hh] + adv);
            xA1 = xwv[(unsigned)sA1 * 8u + hh];
            xB1 = xwv[(unsigned)sB1 * 8u + hh];
            float wA = vA0 ? __builtin_amdgcn_exp2f(eA0 - shift) : 0.f;
            float wB = vB0 ? __builtin_amdgcn_exp2f(eB0 - shift) : 0.f;
            dsum += wA + wB;
            #pragma unroll
            for (int q = 0; q < 4; q++) {
                MIX_LO(accv[2 * q],     xA0[q], wA);
                MIX_HI(accv[2 * q + 1], xA0[q], wA);
            }
            #pragma unroll
            for (int q = 0; q < 4; q++) {
                MIX_LO(accv[2 * q],     xB0[q], wB);
                MIX_HI(accv[2 * q + 1], xB0[q], wB);
            }
            vA0 = vA2; vB0 = vB2; sA0 = nsA; sB0 = nsB;
        }
        j += 4;
        if (!__any(vA1)) break;
        // phase odd: prefetch adj(j+8)->slot1, gathers slot0, compute slot1
        {
            bool vA2 = j + 8 + e2 < re, vB2 = j + 10 + e2 < re;
            int nsA = adj[(unsigned)(vA2 ? j + 8 + e2 : 0)];
            int nsB = adj[(unsigned)(vB2 ? j + 10 + e2 : 0)];
            eA0 = lrelu(as[(unsigned)sA0 * 8u + hh] + adv);
            eB0 = lrelu(as[(unsigned)sB0 * 8u + hh] + adv);
            xA0 = xwv[(unsigned)sA0 * 8u + hh];
            xB0 = xwv[(unsigned)sB0 * 8u + hh];
            float wA = vA1 ? __builtin_amdgcn_exp2f(eA1 - shift) : 0.f;
            float wB = vB1 ? __builtin_amdgcn_exp2f(eB1 - shift) : 0.f;
            dsum += wA + wB;
            #pragma unroll
            for (int q = 0; q < 4; q++) {
                MIX_LO(accv[2 * q],     xA1[q], wA);
                MIX_HI(accv[2 * q + 1], xA1[q], wA);
            }
            #pragma unroll
            for (int q = 0; q < 4; q++) {
                MIX_LO(accv[2 * q],     xB1[q], wB);
                MIX_HI(accv[2 * q + 1], xB1[q], wB);
            }
            vA1 = vA2; vB1 = vB2; sA1 = nsA; sB1 = nsB;
        }
        j += 4;
        if (!__any(vA0)) break;
    }
    #pragma unroll
    for (int k = 0; k < 8; k++) accv[k] += __shfl_xor(accv[k], 8, 64);
    dsum += __shfl_xor(dsum, 8, 64);
    if (e2 == 0) {
        float inv = 1.f / (1.f + dsum);              // self-loop weight = 1
        h8_t sv = *(const h8_t*)(xw + (size_t)n * 64 + hh * 8);
        float4 b0 = *(const float4*)(bias + hh * 8);
        float4 b1 = *(const float4*)(bias + hh * 8 + 4);
        float bb[8] = {b0.x, b0.y, b0.z, b0.w, b1.x, b1.y, b1.z, b1.w};
        h8_t o;
        #pragma unroll
        for (int k = 0; k < 8; k++) {
            float v = (accv[k] + (float)sv[k]) * inv + bb[k];
            o[k] = (_Float16)eluf(v);
        }
        *(h8_t*)(hbuf + (size_t)n * 64 + hh * 8) = o;
    }
}

// ---------------- layer1 transform: h @ W1 via MFMA (K=64) + as1/ad1 --------
__global__ __launch_bounds__(512, 4) void kTF1(
    const __half* __restrict__ h, const float* __restrict__ W1,
    const float* __restrict__ aS1, const float* __restrict__ aD1, int N,
    __half* __restrict__ hw, float* __restrict__ as1, float* __restrict__ ad1)
{
    __shared__ __align__(16) h8_t Bl[512];
    {
        int g = threadIdx.x;                 // 512 threads, one group each
        int col  = g & 15;
        int quad = (g >> 4) & 3;
        int ks   = (g >> 6) & 1;
        int ct   = g >> 7;
        h8_t av;
        #pragma unroll
        for (int j = 0; j < 8; j++) {
            int k = ks * 32 + quad * 8 + j;
            av[j] = (_Float16)W1[k * 64 + ct * 16 + col];
        }
        Bl[g] = av;
    }
    __syncthreads();
    int wave = threadIdx.x >> 6, lane = threadIdx.x & 63;
    int row0 = blockIdx.x * 128 + wave * 16;
    if (row0 >= N) return;
    int quad = lane >> 4, c16 = lane & 15;
    int myrow = min(row0 + c16, N - 1);
    const __half* hr = h + (size_t)myrow * 64;
    h8_t a0 = *(const h8_t*)(hr + quad * 8);
    h8_t a1 = *(const h8_t*)(hr + 32 + quad * 8);
    int rbase = row0 + quad * 4;
    float ps[4] = {0.f, 0.f, 0.f, 0.f};
    float pd[4] = {0.f, 0.f, 0.f, 0.f};
    #pragma unroll
    for (int ct = 0; ct < 4; ct++) {
        f4_t acc = {0.f, 0.f, 0.f, 0.f};
        acc = __builtin_amdgcn_mfma_f32_16x16x32_f16(a0, Bl[(ct * 2 + 0) * 64 + lane], acc, 0, 0, 0);
        acc = __builtin_amdgcn_mfma_f32_16x16x32_f16(a1, Bl[(ct * 2 + 1) * 64 + lane], acc, 0, 0, 0);
        float s1c = aS1[ct * 16 + c16];
        float d1c = aD1[ct * 16 + c16];
        int col = ct * 16 + c16;
        #pragma unroll
        for (int r = 0; r < 4; r++) {
            int rr = rbase + r;
            if (rr < N) hw[(size_t)rr * 64 + col] = __float2half(acc[r]);
            ps[r] = fmaf(acc[r], s1c, ps[r]);
            pd[r] = fmaf(acc[r], d1c, pd[r]);
        }
    }
    #pragma unroll
    for (int r = 0; r < 4; r++) {
        #pragma unroll
        for (int off = 1; off < 16; off <<= 1) {
            ps[r] += __shfl_xor(ps[r], off, 64);
            pd[r] += __shfl_xor(pd[r], off, 64);
        }
    }
    if (c16 == 0) {
        #pragma unroll
        for (int r = 0; r < 4; r++) {
            int rr = rbase + r;
            if (rr < N) { as1[rr] = ps[r] * LOG2E; ad1[rr] = pd[r] * LOG2E; }
        }
    }
}

// ---------------- layer1 aggregation: 4 nodes/wave, depth-2 pipeline --------
__global__ __launch_bounds__(512) void k_agg1(
    const __half* __restrict__ hw, const float* __restrict__ as, const float* __restrict__ ad,
    const int* __restrict__ row, const int* __restrict__ adj,
    const float* __restrict__ bias, int N, float* __restrict__ outp)
{
    int n = (blockIdx.x * 512 + threadIdx.x) >> 4;   // 32 nodes per block
    int sub  = threadIdx.x & 15;
    if (n >= N) return;
    int e2 = sub >> 3;
    int hh = sub & 7;
    int rs = row[n], re = row[n + 1];
    const u4_t* hwv = (const u4_t*)hw;
    float adv = ad[n];
    float shift = lrelu(as[n] + adv);
    float accv[8];
    #pragma unroll
    for (int k = 0; k < 8; k++) accv[k] = 0.f;
    float dsum = 0.f;

    int j = rs;
    bool vA0 = j + e2 < re,     vB0 = j + 2 + e2 < re;
    int  sA0 = adj[(unsigned)(vA0 ? j + e2 : 0)];
    int  sB0 = adj[(unsigned)(vB0 ? j + 2 + e2 : 0)];
    bool vA1 = j + 4 + e2 < re, vB1 = j + 6 + e2 < re;
    int  sA1 = adj[(unsigned)(vA1 ? j + 4 + e2 : 0)];
    int  sB1 = adj[(unsigned)(vB1 ? j + 6 + e2 : 0)];
    float eA0 = lrelu(as[(unsigned)sA0] + adv);
    float eB0 = lrelu(as[(unsigned)sB0] + adv);
    u4_t xA0 = hwv[(unsigned)sA0 * 8u + hh];
    u4_t xB0 = hwv[(unsigned)sB0 * 8u + hh];
    float eA1, eB1; u4_t xA1, xB1;

    for (;;) {
        // phase even
        {
            bool vA2 = j + 8 + e2 < re, vB2 = j + 10 + e2 < re;
            int nsA = adj[(unsigned)(vA2 ? j + 8 + e2 : 0)];
            int nsB = adj[(unsigned)(vB2 ? j + 10 + e2 : 0)];
            eA1 = lrelu(as[(unsigned)sA1] + adv);
            eB1 = lrelu(as[(unsigned)sB1] + adv);
            xA1 = hwv[(unsigned)sA1 * 8u + hh];
            xB1 = hwv[(unsigned)sB1 * 8u + hh];
            float wA = vA0 ? __builtin_amdgcn_exp2f(eA0 - shift) : 0.f;
            float wB = vB0 ? __builtin_amdgcn_exp2f(eB0 - shift) : 0.f;
            dsum += wA + wB;
            #pragma unroll
            for (int q = 0; q < 4; q++) {
                MIX_LO(accv[2 * q],     xA0[q], wA);
                MIX_HI(accv[2 * q + 1], xA0[q], wA);
            }
            #pragma unroll
            for (int q = 0; q < 4; q++) {
                MIX_LO(accv[2 * q],     xB0[q], wB);
                MIX_HI(accv[2 * q + 1], xB0[q], wB);
            }
            vA0 = vA2; vB0 = vB2; sA0 = nsA; sB0 = nsB;
        }
        j += 4;
        if (!__any(vA1)) break;
        // phase odd
        {
            bool vA2 = j + 8 + e2 < re, vB2 = j + 10 + e2 < re;
            int nsA = adj[(unsigned)(vA2 ? j + 8 + e2 : 0)];
            int nsB = adj[(unsigned)(vB2 ? j + 10 + e2 : 0)];
            eA0 = lrelu(as[(unsigned)sA0] + adv);
            eB0 = lrelu(as[(unsigned)sB0] + adv);
            xA0 = hwv[(unsigned)sA0 * 8u + hh];
            xB0 = hwv[(unsigned)sB0 * 8u + hh];
            float wA = vA1 ? __builtin_amdgcn_exp2f(eA1 - shift) : 0.f;
            float wB = vB1 ? __builtin_amdgcn_exp2f(eB1 - shift) : 0.f;
            dsum += wA + wB;
            #pragma unroll
            for (int q = 0; q < 4; q++) {
                MIX_LO(accv[2 * q],     xA1[q], wA);
                MIX_HI(accv[2 * q + 1], xA1[q], wA);
            }
            #pragma unroll
            for (int q = 0; q < 4; q++) {
                MIX_LO(accv[2 * q],     xB1[q], wB);
                MIX_HI(accv[2 * q + 1], xB1[q], wB);
            }
            vA1 = vA2; vB1 = vB2; sA1 = nsA; sB1 = nsB;
        }
        j += 4;
        if (!__any(vA0)) break;
    }
    #pragma unroll
    for (int k = 0; k < 8; k++) accv[k] += __shfl_xor(accv[k], 8, 64);
    dsum += __shfl_xor(dsum, 8, 64);
    if (e2 == 0) {
        float inv = 1.f / (1.f + dsum);
        h8_t sv = *(const h8_t*)(hw + (size_t)n * 64 + hh * 8);
        float4 b0 = *(const float4*)(bias + hh * 8);
        float4 b1 = *(const float4*)(bias + hh * 8 + 4);
        float bb[8] = {b0.x, b0.y, b0.z, b0.w, b1.x, b1.y, b1.z, b1.w};
        float ov[8];
        #pragma unroll
        for (int k = 0; k < 8; k++)
            ov[k] = eluf((accv[k] + (float)sv[k]) * inv + bb[k]);
        float4 o0 = {ov[0], ov[1], ov[2], ov[3]};
        float4 o1 = {ov[4], ov[5], ov[6], ov[7]};
        float4* op = (float4*)(outp + (size_t)n * 64 + hh * 8);
        op[0] = o0;
        op[1] = o1;
    }
}

extern "C" void kernel_launch(void* const* d_in, const int* in_sizes, int n_in,
                              void* d_out, int out_size, void* d_ws, size_t ws_size,
                              hipStream_t stream)
{
    const float* x   = (const float*)d_in[0];
    const int*   ei  = (const int*)d_in[1];
    const float* W0  = (const float*)d_in[2];
    const float* aS0 = (const float*)d_in[3];
    const float* aD0 = (const float*)d_in[4];
    const float* b0  = (const float*)d_in[5];
    const float* W1  = (const float*)d_in[6];
    const float* aS1 = (const float*)d_in[7];
    const float* aD1 = (const float*)d_in[8];
    const float* b1  = (const float*)d_in[9];

    const int N = in_sizes[0] / 128;
    const int E = in_sizes[1] / 2;
    const int* srcp = ei;
    const int* dstp = ei + E;

    const int NB  = (N + 255) >> 8;          // 256-node buckets
    const int cap = E / NB + 4096;

    char* ws = (char*)d_ws;
    size_t off = 0;
    auto alloc = [&](size_t bytes) -> size_t {
        size_t o = off;
        off = (o + bytes + 255) & ~(size_t)255;
        return o;
    };
    __half* B1 = (__half*)(ws + alloc((size_t)N * 64 * 2));     // xw (half); later reused as hw
    size_t b2Bytes = (size_t)N * 64 * 2;
    size_t bkBytes = (size_t)NB * cap * 4;
    char*  region  = ws + alloc(b2Bytes > bkBytes ? b2Bytes : bkBytes);
    __half*   B2        = (__half*)region;     // h overlays bucketBuf (dead after kP2)
    unsigned* bucketBuf = (unsigned*)region;
    float* as0 = (float*)(ws + alloc((size_t)N * 8 * 4));
    float* ad0 = (float*)(ws + alloc((size_t)N * 8 * 4));
    float* as1 = (float*)(ws + alloc((size_t)N * 4));
    float* ad1 = (float*)(ws + alloc((size_t)N * 4));
    int*   row = (int*)(ws + alloc((size_t)(N + 1) * 4));
    int*   adj = (int*)(ws + alloc((size_t)E * 4));
    int*  gcur = (int*)(ws + alloc((size_t)NB * 4));

    const int gemmBlocks = (N + 127) / 128;
    const int binBlocks  = 512;
    const int perBlock   = (E + binBlocks - 1) / binBlocks;

    hipMemsetAsync(gcur, 0, (size_t)NB * 4, stream);
    kGB<<<gemmBlocks + binBlocks, 512, 0, stream>>>(
        x, W0, aS0, aD0, N, B1, as0, ad0, gemmBlocks,
        srcp, dstp, E, perBlock, bucketBuf, gcur, NB, cap, binBlocks);
    kP2<<<NB, 256, 0, stream>>>(bucketBuf, gcur, NB, cap, N, row, adj);

    const int agBlocks = (N + 31) / 32;   // 32 nodes per 512-thread block
    // layer-0 aggregation: reads xw (B1), writes h (B2, over dead bucketBuf)
    k_agg8<<<agBlocks, 512, 0, stream>>>(B1, as0, ad0, row, adj, b0, N, B2);
    // layer-1 transform: reads h (B2), writes hw into B1 (xw dead) + as1/ad1
    kTF1<<<(N + 127) / 128, 512, 0, stream>>>(B2, W1, aS1, aD1, N, B1, as1, ad1);
    // layer-1 aggregation
    k_agg1<<<agBlocks, 512, 0, stream>>>(B1, as1, ad1, row, adj, b1, N, (float*)d_out);
}

// Round 10
// 238.278 us; speedup vs baseline: 1.4213x; 1.0267x over previous
//
#include <hip/hip_runtime.h>
#include <hip/hip_fp16.h>
#include <math.h>

// GAT 2-layer. R23 = R22 resubmit (container failed twice; audit of the fused
// epilogue found no fault/hang class — all barriers uniform, all indices
// bounded, LDS 12.8KB; kGB/kP2/k_agg1 byte-identical to passing R19-R21).
// kTF1 fused into k_agg8's epilogue: producer lanes stage h into padded LDS
// [32][9] h8, one barrier, waves 0-1 run the MFMA matvec (W1 image in LDS)
// and emit hw + as1/ad1. Kills one dispatch + 25.6 MB h HBM round-trip.

#define CAPS 16
#define STRIDE 17
#define NBMAX 512
#define LOG2E 1.44269504f

typedef _Float16 h2_t  __attribute__((ext_vector_type(2)));
typedef _Float16 h8_t  __attribute__((ext_vector_type(8)));
typedef float    f4_t  __attribute__((ext_vector_type(4)));
typedef unsigned int u4_t __attribute__((ext_vector_type(4)));

__device__ __forceinline__ float lrelu(float v) { return v >= 0.f ? v : 0.2f * v; }
__device__ __forceinline__ float eluf(float v)  {
    return v > 0.f ? v : __builtin_amdgcn_exp2f(v * LOG2E) - 1.f;
}

// acc += (float)lo_half(pk) * w   /   acc += (float)hi_half(pk) * w
#define MIX_LO(acc, pk, w) asm("v_fma_mix_f32 %0, %1, %2, %0 op_sel:[0,0,0] op_sel_hi:[1,0,0]" : "+v"(acc) : "v"(pk), "v"(w))
#define MIX_HI(acc, pk, w) asm("v_fma_mix_f32 %0, %1, %2, %0 op_sel:[1,0,0] op_sel_hi:[1,0,0]" : "+v"(acc) : "v"(pk), "v"(w))

// ---------------- tf0 MFMA body: 8 waves/block(512), 16 rows/wave -------------
__device__ __forceinline__ void gemm_body(
    int gb, const float* __restrict__ x, int N,
    __half* __restrict__ xw, float* __restrict__ as, float* __restrict__ ad,
    h8_t* Bl)
{
    int wave = threadIdx.x >> 6, lane = threadIdx.x & 63;
    int row0 = gb * 128 + wave * 16;
    if (row0 >= N) return;
    int quad = lane >> 4, c16 = lane & 15;
    int myrow = min(row0 + c16, N - 1);
    const float* xr = x + (size_t)myrow * 128;
    h8_t a[4];
    #pragma unroll
    for (int ks = 0; ks < 4; ks++) {
        int kb = ks * 32 + quad * 8;
        float4 v0 = *(const float4*)(xr + kb);
        float4 v1 = *(const float4*)(xr + kb + 4);
        h8_t av;
        av[0] = (_Float16)v0.x; av[1] = (_Float16)v0.y;
        av[2] = (_Float16)v0.z; av[3] = (_Float16)v0.w;
        av[4] = (_Float16)v1.x; av[5] = (_Float16)v1.y;
        av[6] = (_Float16)v1.z; av[7] = (_Float16)v1.w;
        a[ks] = av;
    }
    int rbase = row0 + quad * 4;
    #pragma unroll
    for (int ct = 0; ct < 5; ct++) {
        f4_t acc = {0.f, 0.f, 0.f, 0.f};
        #pragma unroll
        for (int ks = 0; ks < 4; ks++) {
            h8_t b = Bl[(ct * 4 + ks) * 64 + lane];
            acc = __builtin_amdgcn_mfma_f32_16x16x32_f16(a[ks], b, acc, 0, 0, 0);
        }
        if (ct < 4) {
            int col = ct * 16 + c16;
            #pragma unroll
            for (int r = 0; r < 4; r++) {
                int row = rbase + r;
                if (row < N) xw[(size_t)row * 64 + col] = __float2half(acc[r]);
            }
        } else {
            #pragma unroll
            for (int r = 0; r < 4; r++) {
                int row = rbase + r;
                if (row < N) {
                    float sc = acc[r] * LOG2E;   // pre-scale logits: exp -> exp2
                    if (c16 < 8) as[(size_t)row * 8 + c16] = sc;
                    else         ad[(size_t)row * 8 + (c16 - 8)] = sc;
                }
            }
        }
    }
}

// ---------------- fused: gemm0 || single-pass binning ----------------
__global__ __launch_bounds__(512, 4) void kGB(
    const float* __restrict__ x, const float* __restrict__ W0,
    const float* __restrict__ aS0, const float* __restrict__ aD0, int N,
    __half* __restrict__ xw, float* __restrict__ as, float* __restrict__ ad,
    int gemmBlocks,
    const int* __restrict__ src, const int* __restrict__ dst, int E, int perBlock,
    unsigned* __restrict__ bucketBuf, int* __restrict__ gcur, int NB, int cap,
    int binBlocks)
{
    __shared__ __align__(16) char smem[NBMAX * STRIDE * 4 + NBMAX * 4]; // 36.9 KB union
    int b = blockIdx.x;
    int T = gemmBlocks + binBlocks;
    int lo = (int)((long long)b * gemmBlocks / T);
    int hi = (int)((long long)(b + 1) * gemmBlocks / T);
    if (hi > lo) {
        h8_t* Bl = (h8_t*)smem;
        for (int g = threadIdx.x; g < 1280; g += 512) {
            int col  = g & 15;
            int quad = (g >> 4) & 3;
            int ks   = (g >> 6) & 3;
            int ct   = g >> 8;
            h8_t av;
            if (ct < 4) {
                #pragma unroll
                for (int j = 0; j < 8; j++) {
                    int k = ks * 32 + quad * 8 + j;
                    av[j] = (_Float16)W0[k * 64 + ct * 16 + col];
                }
            } else {
                int h = col & 7;
                const float* att = (col < 8) ? aS0 : aD0;
                #pragma unroll
                for (int j = 0; j < 8; j++) {
                    int k = ks * 32 + quad * 8 + j;
                    float v = 0.f;
                    #pragma unroll
                    for (int cc = 0; cc < 8; cc++)
                        v += W0[k * 64 + h * 8 + cc] * att[h * 8 + cc];
                    av[j] = (_Float16)v;
                }
            }
            Bl[g] = av;
        }
        __syncthreads();
        gemm_body(lo, x, N, xw, as, ad, Bl);
    } else {
        int pb = b - hi;
        unsigned* stage = (unsigned*)smem;
        int* scnt = (int*)(smem + NBMAX * STRIDE * 4);
        int tid = threadIdx.x;
        for (int i = tid; i < NB; i += 512) scnt[i] = 0;
        __syncthreads();
        int e0 = pb * perBlock, e1 = min(E, e0 + perBlock);
        for (int i = e0 + tid; i < e1; i += 512) {
            int d2 = dst[i], s2 = src[i];
            int bk = d2 >> 8;                              // 256-node buckets
            unsigned rec = ((unsigned)(d2 & 255) << 22) | (unsigned)s2;
            int pos = atomicAdd(&scnt[bk], 1);
            if (pos < CAPS) {
                stage[bk * STRIDE + pos] = rec;
            } else {
                int g = atomicAdd(&gcur[bk], 1);
                if (g < cap) bucketBuf[(size_t)bk * cap + g] = rec;
            }
        }
        __syncthreads();
        for (int t = tid; t < NB; t += 512) {
            int n = min(scnt[t], CAPS);
            if (n > 0) {
                int gb2 = atomicAdd(&gcur[t], n);
                unsigned* gp = &bucketBuf[(size_t)t * cap + gb2];
                for (int j = 0; j < n; j++)
                    if (gb2 + j < cap) gp[j] = stage[t * STRIDE + j];
            }
        }
    }
}

// ---------------- phase2: per-bucket CSR build (256-node buckets) ----------
__global__ __launch_bounds__(256) void kP2(
    const unsigned* __restrict__ bucketBuf, const int* __restrict__ gcur,
    int NB, int cap, int N, int* __restrict__ row, int* __restrict__ adj)
{
    __shared__ int deg[256];
    __shared__ int curl[256];
    __shared__ int sc[256];
    int b = blockIdx.x, tid = threadIdx.x;
    int lo = b << 8;
    int hi = min(N, lo + 256);
    int cnt = hi - lo;
    int size = min(gcur[b], cap);
    int part = 0;
    for (int i = tid; i < b; i += 256) part += min(gcur[i], cap);
    sc[tid] = part;
    __syncthreads();
    for (int off = 128; off > 0; off >>= 1) {
        if (tid < off) sc[tid] += sc[tid + off];
        __syncthreads();
    }
    int bbase = sc[0];
    __syncthreads();
    deg[tid] = 0;
    __syncthreads();
    const unsigned* buf = bucketBuf + (size_t)b * cap;
    for (int e = tid; e < size; e += 256) atomicAdd(&deg[buf[e] >> 22], 1);
    __syncthreads();
    int d = deg[tid];
    sc[tid] = d;
    __syncthreads();
    for (int off = 1; off < 256; off <<= 1) {
        int xv = (tid >= off) ? sc[tid - off] : 0;
        __syncthreads();
        sc[tid] += xv;
        __syncthreads();
    }
    int o = (tid ? sc[tid - 1] : 0);
    curl[tid] = o;
    if (tid < cnt) row[lo + tid] = bbase + o;
    if (b == NB - 1 && tid == 0) row[N] = bbase + size;
    __syncthreads();
    for (int e = tid; e < size; e += 256) {
        unsigned r = buf[e];
        int l = r >> 22;
        int p = atomicAdd(&curl[l], 1);
        adj[bbase + p] = (int)(r & 0x3FFFFF);
    }
}

// ---------------- layer0 agg (4 nodes/wave) + fused layer1 transform -------
__global__ __launch_bounds__(512) void k_agg8(
    const __half* __restrict__ xw, const float* __restrict__ as, const float* __restrict__ ad,
    const int* __restrict__ row, const int* __restrict__ adj,
    const float* __restrict__ bias,
    const float* __restrict__ W1, const float* __restrict__ aS1, const float* __restrict__ aD1,
    int N, __half* __restrict__ hw, float* __restrict__ as1, float* __restrict__ ad1)
{
    __shared__ __align__(16) h8_t Wl[512];     // W1 image [ct][ks][quad][col]
    __shared__ __align__(16) h8_t hst[32][9];  // h chunks, padded stride
    {
        int g = threadIdx.x;
        int col  = g & 15;
        int quad = (g >> 4) & 3;
        int ks   = (g >> 6) & 1;
        int ct   = g >> 7;
        h8_t av;
        #pragma unroll
        for (int j = 0; j < 8; j++) {
            int k = ks * 32 + quad * 8 + j;
            av[j] = (_Float16)W1[k * 64 + ct * 16 + col];
        }
        Wl[g] = av;
    }
    int n = (blockIdx.x * 512 + threadIdx.x) >> 4;   // 32 nodes per block
    int sub  = threadIdx.x & 15;
    bool active = n < N;
    int e2 = sub >> 3;
    int hh = sub & 7;
    int rs = active ? row[n] : 0;
    int re = active ? row[n + 1] : 0;
    const u4_t* xwv = (const u4_t*)xw;               // row stride = 8 chunks
    unsigned nc = active ? (unsigned)n : 0u;
    float adv = ad[nc * 8u + hh];
    float shift = lrelu(as[nc * 8u + hh] + adv);
    float accv[8];
    #pragma unroll
    for (int k = 0; k < 8; k++) accv[k] = 0.f;
    float dsum = 0.f;

    int j = rs;
    bool vA0 = j + e2 < re,     vB0 = j + 2 + e2 < re;
    int  sA0 = adj[(unsigned)(vA0 ? j + e2 : 0)];
    int  sB0 = adj[(unsigned)(vB0 ? j + 2 + e2 : 0)];
    bool vA1 = j + 4 + e2 < re, vB1 = j + 6 + e2 < re;
    int  sA1 = adj[(unsigned)(vA1 ? j + 4 + e2 : 0)];
    int  sB1 = adj[(unsigned)(vB1 ? j + 6 + e2 : 0)];
    float eA0 = lrelu(as[(unsigned)sA0 * 8u + hh] + adv);
    float eB0 = lrelu(as[(unsigned)sB0 * 8u + hh] + adv);
    u4_t xA0 = xwv[(unsigned)sA0 * 8u + hh];
    u4_t xB0 = xwv[(unsigned)sB0 * 8u + hh];
    float eA1, eB1; u4_t xA1, xB1;

    for (;;) {
        // phase even: prefetch adj(j+8)->slot0, gathers slot1, compute slot0
        {
            bool vA2 = j + 8 + e2 < re, vB2 = j + 10 + e2 < re;
            int nsA = adj[(unsigned)(vA2 ? j + 8 + e2 : 0)];
            int nsB = adj[(unsigned)(vB2 ? j + 10 + e2 : 0)];
            eA1 = lrelu(as[(unsigned)sA1 * 8u + hh] + adv);
            eB1 = lrelu(as[(unsigned)sB1 * 8u + hh] + adv);
            xA1 = xwv[(unsigned)sA1 * 8u + hh];
            xB1 = xwv[(unsigned)sB1 * 8u + hh];
            float wA = vA0 ? __builtin_amdgcn_exp2f(eA0 - shift) : 0.f;
            float wB = vB0 ? __builtin_amdgcn_exp2f(eB0 - shift) : 0.f;
            dsum += wA + wB;
            #pragma unroll
            for (int q = 0; q < 4; q++) {
                MIX_LO(accv[2 * q],     xA0[q], wA);
                MIX_HI(accv[2 * q + 1], xA0[q], wA);
            }
            #pragma unroll
            for (int q = 0; q < 4; q++) {
                MIX_LO(accv[2 * q],     xB0[q], wB);
                MIX_HI(accv[2 * q + 1], xB0[q], wB);
            }
            vA0 = vA2; vB0 = vB2; sA0 = nsA; sB0 = nsB;
        }
        j += 4;
        if (!__any(vA1)) break;
        // phase odd: prefetch adj(j+8)->slot1, gathers slot0, compute slot1
        {
            bool vA2 = j + 8 + e2 < re, vB2 = j + 10 + e2 < re;
            int nsA = adj[(unsigned)(vA2 ? j + 8 + e2 : 0)];
            int nsB = adj[(unsigned)(vB2 ? j + 10 + e2 : 0)];
            eA0 = lrelu(as[(unsigned)sA0 * 8u + hh] + adv);
            eB0 = lrelu(as[(unsigned)sB0 * 8u + hh] + adv);
            xA0 = xwv[(unsigned)sA0 * 8u + hh];
            xB0 = xwv[(unsigned)sB0 * 8u + hh];
            float wA = vA1 ? __builtin_amdgcn_exp2f(eA1 - shift) : 0.f;
            float wB = vB1 ? __builtin_amdgcn_exp2f(eB1 - shift) : 0.f;
            dsum += wA + wB;
            #pragma unroll
            for (int q = 0; q < 4; q++) {
                MIX_LO(accv[2 * q],     xA1[q], wA);
                MIX_HI(accv[2 * q + 1], xA1[q], wA);
            }
            #pragma unroll
            for (int q = 0; q < 4; q++) {
                MIX_LO(accv[2 * q],     xB1[q], wB);
                MIX_HI(accv[2 * q + 1], xB1[q], wB);
            }
            vA1 = vA2; vB1 = vB2; sA1 = nsA; sB1 = nsB;
        }
        j += 4;
        if (!__any(vA0)) break;
    }
    #pragma unroll
    for (int k = 0; k < 8; k++) accv[k] += __shfl_xor(accv[k], 8, 64);
    dsum += __shfl_xor(dsum, 8, 64);
    if (e2 == 0) {
        int nl = (threadIdx.x >> 4);                 // local node 0..31
        h8_t o;
        if (active) {
            float inv = 1.f / (1.f + dsum);          // self-loop weight = 1
            h8_t sv = *(const h8_t*)(xw + (size_t)n * 64 + hh * 8);
            float4 b0 = *(const float4*)(bias + hh * 8);
            float4 b1 = *(const float4*)(bias + hh * 8 + 4);
            float bb[8] = {b0.x, b0.y, b0.z, b0.w, b1.x, b1.y, b1.z, b1.w};
            #pragma unroll
            for (int k = 0; k < 8; k++) {
                float v = (accv[k] + (float)sv[k]) * inv + bb[k];
                o[k] = (_Float16)eluf(v);
            }
        } else {
            #pragma unroll
            for (int k = 0; k < 8; k++) o[k] = (_Float16)0.f;
        }
        hst[nl][hh] = o;
    }
    __syncthreads();
    // ---- fused TF1: waves 0-1 compute hw = h @ W1 (+ as1/ad1) for 32 rows ---
    int wave = threadIdx.x >> 6, lane = threadIdx.x & 63;
    if (wave < 2) {
        int quad = lane >> 4, c16 = lane & 15;
        int lrow = wave * 16 + c16;                  // local row 0..31
        int row0 = blockIdx.x * 32 + wave * 16;
        h8_t a0 = hst[lrow][quad];
        h8_t a1 = hst[lrow][4 + quad];
        int rbase = row0 + quad * 4;
        float ps[4] = {0.f, 0.f, 0.f, 0.f};
        float pd[4] = {0.f, 0.f, 0.f, 0.f};
        #pragma unroll
        for (int ct = 0; ct < 4; ct++) {
            f4_t acc = {0.f, 0.f, 0.f, 0.f};
            acc = __builtin_amdgcn_mfma_f32_16x16x32_f16(a0, Wl[(ct * 2 + 0) * 64 + lane], acc, 0, 0, 0);
            acc = __builtin_amdgcn_mfma_f32_16x16x32_f16(a1, Wl[(ct * 2 + 1) * 64 + lane], acc, 0, 0, 0);
            float s1c = aS1[ct * 16 + c16];
            float d1c = aD1[ct * 16 + c16];
            int col = ct * 16 + c16;
            #pragma unroll
            for (int r = 0; r < 4; r++) {
                int rr = rbase + r;
                if (rr < N) hw[(size_t)rr * 64 + col] = __float2half(acc[r]);
                ps[r] = fmaf(acc[r], s1c, ps[r]);
                pd[r] = fmaf(acc[r], d1c, pd[r]);
            }
        }
        #pragma unroll
        for (int r = 0; r < 4; r++) {
            #pragma unroll
            for (int off = 1; off < 16; off <<= 1) {
                ps[r] += __shfl_xor(ps[r], off, 64);
                pd[r] += __shfl_xor(pd[r], off, 64);
            }
        }
        if (c16 == 0) {
            #pragma unroll
            for (int r = 0; r < 4; r++) {
                int rr = rbase + r;
                if (rr < N) { as1[rr] = ps[r] * LOG2E; ad1[rr] = pd[r] * LOG2E; }
            }
        }
    }
}

// ---------------- layer1 aggregation: 4 nodes/wave, depth-2 pipeline --------
__global__ __launch_bounds__(512) void k_agg1(
    const __half* __restrict__ hw, const float* __restrict__ as, const float* __restrict__ ad,
    const int* __restrict__ row, const int* __restrict__ adj,
    const float* __restrict__ bias, int N, float* __restrict__ outp)
{
    int n = (blockIdx.x * 512 + threadIdx.x) >> 4;   // 32 nodes per block
    int sub  = threadIdx.x & 15;
    if (n >= N) return;
    int e2 = sub >> 3;
    int hh = sub & 7;
    int rs = row[n], re = row[n + 1];
    const u4_t* hwv = (const u4_t*)hw;
    float adv = ad[n];
    float shift = lrelu(as[n] + adv);
    float accv[8];
    #pragma unroll
    for (int k = 0; k < 8; k++) accv[k] = 0.f;
    float dsum = 0.f;

    int j = rs;
    bool vA0 = j + e2 < re,     vB0 = j + 2 + e2 < re;
    int  sA0 = adj[(unsigned)(vA0 ? j + e2 : 0)];
    int  sB0 = adj[(unsigned)(vB0 ? j + 2 + e2 : 0)];
    bool vA1 = j + 4 + e2 < re, vB1 = j + 6 + e2 < re;
    int  sA1 = adj[(unsigned)(vA1 ? j + 4 + e2 : 0)];
    int  sB1 = adj[(unsigned)(vB1 ? j + 6 + e2 : 0)];
    float eA0 = lrelu(as[(unsigned)sA0] + adv);
    float eB0 = lrelu(as[(unsigned)sB0] + adv);
    u4_t xA0 = hwv[(unsigned)sA0 * 8u + hh];
    u4_t xB0 = hwv[(unsigned)sB0 * 8u + hh];
    float eA1, eB1; u4_t xA1, xB1;

    for (;;) {
        // phase even
        {
            bool vA2 = j + 8 + e2 < re, vB2 = j + 10 + e2 < re;
            int nsA = adj[(unsigned)(vA2 ? j + 8 + e2 : 0)];
            int nsB = adj[(unsigned)(vB2 ? j + 10 + e2 : 0)];
            eA1 = lrelu(as[(unsigned)sA1] + adv);
            eB1 = lrelu(as[(unsigned)sB1] + adv);
            xA1 = hwv[(unsigned)sA1 * 8u + hh];
            xB1 = hwv[(unsigned)sB1 * 8u + hh];
            float wA = vA0 ? __builtin_amdgcn_exp2f(eA0 - shift) : 0.f;
            float wB = vB0 ? __builtin_amdgcn_exp2f(eB0 - shift) : 0.f;
            dsum += wA + wB;
            #pragma unroll
            for (int q = 0; q < 4; q++) {
                MIX_LO(accv[2 * q],     xA0[q], wA);
                MIX_HI(accv[2 * q + 1], xA0[q], wA);
            }
            #pragma unroll
            for (int q = 0; q < 4; q++) {
                MIX_LO(accv[2 * q],     xB0[q], wB);
                MIX_HI(accv[2 * q + 1], xB0[q], wB);
            }
            vA0 = vA2; vB0 = vB2; sA0 = nsA; sB0 = nsB;
        }
        j += 4;
        if (!__any(vA1)) break;
        // phase odd
        {
            bool vA2 = j + 8 + e2 < re, vB2 = j + 10 + e2 < re;
            int nsA = adj[(unsigned)(vA2 ? j + 8 + e2 : 0)];
            int nsB = adj[(unsigned)(vB2 ? j + 10 + e2 : 0)];
            eA0 = lrelu(as[(unsigned)sA0] + adv);
            eB0 = lrelu(as[(unsigned)sB0] + adv);
            xA0 = hwv[(unsigned)sA0 * 8u + hh];
            xB0 = hwv[(unsigned)sB0 * 8u + hh];
            float wA = vA1 ? __builtin_amdgcn_exp2f(eA1 - shift) : 0.f;
            float wB = vB1 ? __builtin_amdgcn_exp2f(eB1 - shift) : 0.f;
            dsum += wA + wB;
            #pragma unroll
            for (int q = 0; q < 4; q++) {
                MIX_LO(accv[2 * q],     xA1[q], wA);
                MIX_HI(accv[2 * q + 1], xA1[q], wA);
            }
            #pragma unroll
            for (int q = 0; q < 4; q++) {
                MIX_LO(accv[2 * q],     xB1[q], wB);
                MIX_HI(accv[2 * q + 1], xB1[q], wB);
            }
            vA1 = vA2; vB1 = vB2; sA1 = nsA; sB1 = nsB;
        }
        j += 4;
        if (!__any(vA0)) break;
    }
    #pragma unroll
    for (int k = 0; k < 8; k++) accv[k] += __shfl_xor(accv[k], 8, 64);
    dsum += __shfl_xor(dsum, 8, 64);
    if (e2 == 0) {
        float inv = 1.f / (1.f + dsum);
        h8_t sv = *(const h8_t*)(hw + (size_t)n * 64 + hh * 8);
        float4 b0 = *(const float4*)(bias + hh * 8);
        float4 b1 = *(const float4*)(bias + hh * 8 + 4);
        float bb[8] = {b0.x, b0.y, b0.z, b0.w, b1.x, b1.y, b1.z, b1.w};
        float ov[8];
        #pragma unroll
        for (int k = 0; k < 8; k++)
            ov[k] = eluf((accv[k] + (float)sv[k]) * inv + bb[k]);
        float4 o0 = {ov[0], ov[1], ov[2], ov[3]};
        float4 o1 = {ov[4], ov[5], ov[6], ov[7]};
        float4* op = (float4*)(outp + (size_t)n * 64 + hh * 8);
        op[0] = o0;
        op[1] = o1;
    }
}

extern "C" void kernel_launch(void* const* d_in, const int* in_sizes, int n_in,
                              void* d_out, int out_size, void* d_ws, size_t ws_size,
                              hipStream_t stream)
{
    const float* x   = (const float*)d_in[0];
    const int*   ei  = (const int*)d_in[1];
    const float* W0  = (const float*)d_in[2];
    const float* aS0 = (const float*)d_in[3];
    const float* aD0 = (const float*)d_in[4];
    const float* b0  = (const float*)d_in[5];
    const float* W1  = (const float*)d_in[6];
    const float* aS1 = (const float*)d_in[7];
    const float* aD1 = (const float*)d_in[8];
    const float* b1  = (const float*)d_in[9];

    const int N = in_sizes[0] / 128;
    const int E = in_sizes[1] / 2;
    const int* srcp = ei;
    const int* dstp = ei + E;

    const int NB  = (N + 255) >> 8;          // 256-node buckets
    const int cap = E / NB + 4096;

    char* ws = (char*)d_ws;
    size_t off = 0;
    auto alloc = [&](size_t bytes) -> size_t {
        size_t o = off;
        off = (o + bytes + 255) & ~(size_t)255;
        return o;
    };
    __half* B1 = (__half*)(ws + alloc((size_t)N * 64 * 2));     // xw (half)
    size_t b2Bytes = (size_t)N * 64 * 2;
    size_t bkBytes = (size_t)NB * cap * 4;
    char*  region  = ws + alloc(b2Bytes > bkBytes ? b2Bytes : bkBytes);
    __half*   B2        = (__half*)region;     // hw overlays bucketBuf (dead after kP2)
    unsigned* bucketBuf = (unsigned*)region;
    float* as0 = (float*)(ws + alloc((size_t)N * 8 * 4));
    float* ad0 = (float*)(ws + alloc((size_t)N * 8 * 4));
    float* as1 = (float*)(ws + alloc((size_t)N * 4));
    float* ad1 = (float*)(ws + alloc((size_t)N * 4));
    int*   row = (int*)(ws + alloc((size_t)(N + 1) * 4));
    int*   adj = (int*)(ws + alloc((size_t)E * 4));
    int*  gcur = (int*)(ws + alloc((size_t)NB * 4));

    const int gemmBlocks = (N + 127) / 128;
    const int binBlocks  = 512;
    const int perBlock   = (E + binBlocks - 1) / binBlocks;

    hipMemsetAsync(gcur, 0, (size_t)NB * 4, stream);
    kGB<<<gemmBlocks + binBlocks, 512, 0, stream>>>(
        x, W0, aS0, aD0, N, B1, as0, ad0, gemmBlocks,
        srcp, dstp, E, perBlock, bucketBuf, gcur, NB, cap, binBlocks);
    kP2<<<NB, 256, 0, stream>>>(bucketBuf, gcur, NB, cap, N, row, adj);

    const int agBlocks = (N + 31) / 32;   // 32 nodes per 512-thread block
    // layer-0 aggregation + fused layer-1 transform:
    // reads xw (B1), writes hw (B2, over dead bucketBuf) + as1/ad1
    k_agg8<<<agBlocks, 512, 0, stream>>>(B1, as0, ad0, row, adj, b0,
                                         W1, aS1, aD1, N, B2, as1, ad1);
    // layer-1 aggregation
    k_agg1<<<agBlocks, 512, 0, stream>>>(B2, as1, ad1, row, adj, b1, N, (float*)d_out);
}